// Round 1
// baseline (981.137 us; speedup 1.0000x reference)
//
#include <hip/hip_runtime.h>

static inline int cdiv(int a, int b) { return (a + b - 1) / b; }

// ---------------- CSR build ----------------

__global__ __launch_bounds__(256) void count_k(const int* __restrict__ col, int E,
                                               int* __restrict__ cnt) {
  int i = blockIdx.x * 256 + threadIdx.x;
  if (i < E) atomicAdd(&cnt[col[i]], 1);
}

__global__ __launch_bounds__(256) void scan1_k(const int* __restrict__ cnt, int n,
                                               int* __restrict__ rowptr,
                                               int* __restrict__ bsum) {
  __shared__ int sm[256];
  int t = threadIdx.x;
  int i = blockIdx.x * 256 + t;
  int v = (i < n) ? cnt[i] : 0;
  sm[t] = v;
  __syncthreads();
  for (int off = 1; off < 256; off <<= 1) {
    int x = (t >= off) ? sm[t - off] : 0;
    __syncthreads();
    if (t >= off) sm[t] += x;
    __syncthreads();
  }
  if (i < n) rowptr[i] = sm[t] - v;  // exclusive
  if (t == 0) bsum[blockIdx.x] = sm[255];
}

__global__ __launch_bounds__(256) void scan2_k(const int* __restrict__ bsum, int nb,
                                               int* __restrict__ boff) {
  __shared__ int sm[256];
  int t = threadIdx.x;
  int v = (t < nb) ? bsum[t] : 0;
  sm[t] = v;
  __syncthreads();
  for (int off = 1; off < 256; off <<= 1) {
    int x = (t >= off) ? sm[t - off] : 0;
    __syncthreads();
    if (t >= off) sm[t] += x;
    __syncthreads();
  }
  boff[t] = sm[t] - v;  // exclusive
}

__global__ __launch_bounds__(256) void scan3_k(int* __restrict__ rowptr, int n,
                                               const int* __restrict__ boff,
                                               int* __restrict__ cursor, int Etot) {
  int i = blockIdx.x * 256 + threadIdx.x;
  if (i < n) {
    int v = rowptr[i] + boff[blockIdx.x];
    rowptr[i] = v;
    cursor[i] = v;
  }
  if (i == 0) rowptr[n] = Etot;
}

__global__ __launch_bounds__(256) void fill_k(const int* __restrict__ row,
                                              const int* __restrict__ col, int E,
                                              int* __restrict__ cursor,
                                              int* __restrict__ csr) {
  int i = blockIdx.x * 256 + threadIdx.x;
  if (i < E) {
    int p = atomicAdd(&cursor[col[i]], 1);
    csr[p] = row[i];
  }
}

// ---------------- mean aggregation (gather over CSR) ----------------
// one wave per destination node; 128 floats -> float2 per lane (512B/edge)

__global__ __launch_bounds__(256) void agg_mean_k(const float* __restrict__ xsrc,
                                                  const int* __restrict__ rowptr,
                                                  const int* __restrict__ csr, int n_dst,
                                                  float* __restrict__ outm) {
  int node = blockIdx.x * 4 + (threadIdx.x >> 6);
  if (node >= n_dst) return;
  int lane = threadIdx.x & 63;
  int s = rowptr[node], e = rowptr[node + 1];
  float ax = 0.f, ay = 0.f;
  int i = s;
  for (; i + 4 <= e; i += 4) {
    int i0 = csr[i], i1 = csr[i + 1], i2 = csr[i + 2], i3 = csr[i + 3];
    const float2 v0 = *reinterpret_cast<const float2*>(xsrc + (size_t)i0 * 128 + lane * 2);
    const float2 v1 = *reinterpret_cast<const float2*>(xsrc + (size_t)i1 * 128 + lane * 2);
    const float2 v2 = *reinterpret_cast<const float2*>(xsrc + (size_t)i2 * 128 + lane * 2);
    const float2 v3 = *reinterpret_cast<const float2*>(xsrc + (size_t)i3 * 128 + lane * 2);
    ax += (v0.x + v1.x) + (v2.x + v3.x);
    ay += (v0.y + v1.y) + (v2.y + v3.y);
  }
  for (; i < e; ++i) {
    int i0 = csr[i];
    const float2 v0 = *reinterpret_cast<const float2*>(xsrc + (size_t)i0 * 128 + lane * 2);
    ax += v0.x;
    ay += v0.y;
  }
  float inv = (e > s) ? 1.f / (float)(e - s) : 0.f;
  float2 r;
  r.x = ax * inv;
  r.y = ay * inv;
  *reinterpret_cast<float2*>(outm + (size_t)node * 128 + lane * 2) = r;
}

// ---------------- fused dual GEMM:  out = A0@W0 + A1@W1 + bias ----------------
// Treated as single K=256 GEMM with concatenated A' = [A0|A1], W' = [W0;W1].
// A0,A1: [M][128], W0,W1: [128][COUT], out: [M][COUT]

template <int COUT>
__global__ __launch_bounds__(256) void gemm_dual_k(const float* __restrict__ A0,
                                                   const float* __restrict__ A1,
                                                   const float* __restrict__ W0,
                                                   const float* __restrict__ W1,
                                                   const float* __restrict__ bias,
                                                   float* __restrict__ out, int M) {
  constexpr int TX = COUT / 8;   // 16 (COUT=128) or 8 (COUT=64)
  constexpr int TY = 256 / TX;   // 16 or 32
  constexpr int ROWS = TY * 4;   // 64 or 128
  constexpr int KC = 32;

  __shared__ float Alds[ROWS][KC + 1];
  __shared__ float Wlds[KC][COUT];

  const int tid = threadIdx.x;
  const int tx = tid % TX;
  const int ty = tid / TX;
  const int c0 = tx * 8;
  const int r0 = ty * 4;
  const int rowBase = blockIdx.x * ROWS;

  float acc[4][8];
#pragma unroll
  for (int i = 0; i < 4; ++i)
#pragma unroll
    for (int j = 0; j < 8; ++j) acc[i][j] = 0.f;

  for (int kc = 0; kc < 8; ++kc) {  // 8 chunks of 32 over K=256
    const float* Asrc = (kc < 4) ? A0 : A1;
    const float* Wsrc = (kc < 4) ? W0 : W1;
    const int kbase = (kc & 3) * KC;

    // stage A chunk: ROWS x 32 (float4 loads, coalesced)
    {
      constexpr int ITER = (ROWS * KC) / (256 * 4);  // 2 or 4
#pragma unroll
      for (int it = 0; it < ITER; ++it) {
        int idx = it * 256 + tid;
        int rr = idx / 8;
        int kk = (idx % 8) * 4;
        int gr = rowBase + rr;
        float4 v = make_float4(0.f, 0.f, 0.f, 0.f);
        if (gr < M) v = *reinterpret_cast<const float4*>(Asrc + (size_t)gr * 128 + kbase + kk);
        Alds[rr][kk + 0] = v.x;
        Alds[rr][kk + 1] = v.y;
        Alds[rr][kk + 2] = v.z;
        Alds[rr][kk + 3] = v.w;
      }
    }
    // stage W chunk: 32 x COUT
    {
      constexpr int ITER = (KC * COUT) / (256 * 4);  // 4 or 2
#pragma unroll
      for (int it = 0; it < ITER; ++it) {
        int idx = it * 256 + tid;
        int kk = idx / (COUT / 4);
        int cc = (idx % (COUT / 4)) * 4;
        float4 v = *reinterpret_cast<const float4*>(Wsrc + (size_t)(kbase + kk) * COUT + cc);
        *reinterpret_cast<float4*>(&Wlds[kk][cc]) = v;
      }
    }
    __syncthreads();

#pragma unroll
    for (int k = 0; k < KC; ++k) {
      float a0 = Alds[r0 + 0][k];
      float a1 = Alds[r0 + 1][k];
      float a2 = Alds[r0 + 2][k];
      float a3 = Alds[r0 + 3][k];
      const float4 w0 = *reinterpret_cast<const float4*>(&Wlds[k][c0]);
      const float4 w1 = *reinterpret_cast<const float4*>(&Wlds[k][c0 + 4]);
      acc[0][0] += a0 * w0.x; acc[0][1] += a0 * w0.y; acc[0][2] += a0 * w0.z; acc[0][3] += a0 * w0.w;
      acc[0][4] += a0 * w1.x; acc[0][5] += a0 * w1.y; acc[0][6] += a0 * w1.z; acc[0][7] += a0 * w1.w;
      acc[1][0] += a1 * w0.x; acc[1][1] += a1 * w0.y; acc[1][2] += a1 * w0.z; acc[1][3] += a1 * w0.w;
      acc[1][4] += a1 * w1.x; acc[1][5] += a1 * w1.y; acc[1][6] += a1 * w1.z; acc[1][7] += a1 * w1.w;
      acc[2][0] += a2 * w0.x; acc[2][1] += a2 * w0.y; acc[2][2] += a2 * w0.z; acc[2][3] += a2 * w0.w;
      acc[2][4] += a2 * w1.x; acc[2][5] += a2 * w1.y; acc[2][6] += a2 * w1.z; acc[2][7] += a2 * w1.w;
      acc[3][0] += a3 * w0.x; acc[3][1] += a3 * w0.y; acc[3][2] += a3 * w0.z; acc[3][3] += a3 * w0.w;
      acc[3][4] += a3 * w1.x; acc[3][5] += a3 * w1.y; acc[3][6] += a3 * w1.z; acc[3][7] += a3 * w1.w;
    }
    __syncthreads();
  }

  float b[8];
#pragma unroll
  for (int j = 0; j < 8; ++j) b[j] = bias[c0 + j];

#pragma unroll
  for (int i = 0; i < 4; ++i) {
    int gr = rowBase + r0 + i;
    if (gr < M) {
      float4 v0, v1;
      v0.x = acc[i][0] + b[0]; v0.y = acc[i][1] + b[1];
      v0.z = acc[i][2] + b[2]; v0.w = acc[i][3] + b[3];
      v1.x = acc[i][4] + b[4]; v1.y = acc[i][5] + b[5];
      v1.z = acc[i][6] + b[6]; v1.w = acc[i][7] + b[7];
      *reinterpret_cast<float4*>(out + (size_t)gr * COUT + c0) = v0;
      *reinterpret_cast<float4*>(out + (size_t)gr * COUT + c0 + 4) = v1;
    }
  }
}

// ---------------- launch ----------------

extern "C" void kernel_launch(void* const* d_in, const int* in_sizes, int n_in,
                              void* d_out, int out_size, void* d_ws, size_t ws_size,
                              hipStream_t stream) {
  const float* x_s = (const float*)d_in[0];
  const float* x_t = (const float*)d_in[1];
  const int* s2t = (const int*)d_in[2];
  const int* t2s = (const int*)d_in[3];
  const float* W1s_l = (const float*)d_in[4];
  const float* W1s_r = (const float*)d_in[5];
  const float* b1s = (const float*)d_in[6];
  const float* W1t_l = (const float*)d_in[7];
  const float* W1t_r = (const float*)d_in[8];
  const float* b1t = (const float*)d_in[9];
  const float* W2s_l = (const float*)d_in[10];
  const float* W2s_r = (const float*)d_in[11];
  const float* b2s = (const float*)d_in[12];
  const float* W2t_l = (const float*)d_in[13];
  const float* W2t_r = (const float*)d_in[14];
  const float* b2t = (const float*)d_in[15];

  const int NS = in_sizes[0] / 128;
  const int NT = in_sizes[1] / 128;
  const int E = in_sizes[2] / 2;

  char* ws = (char*)d_ws;
  size_t off = 0;
  auto alloc = [&](size_t bytes) -> void* {
    void* p = ws + off;
    off = (off + bytes + 255) & ~(size_t)255;
    return p;
  };

  int* cnt_s = (int*)alloc((size_t)NS * 4);
  int* cnt_t = (int*)alloc((size_t)NT * 4);
  int* rowptr_s = (int*)alloc((size_t)(NS + 1) * 4);
  int* rowptr_t = (int*)alloc((size_t)(NT + 1) * 4);
  int* cursor_s = (int*)alloc((size_t)NS * 4);
  int* cursor_t = (int*)alloc((size_t)NT * 4);
  int* bsum = (int*)alloc(256 * 4);
  int* boff = (int*)alloc(256 * 4);
  int* csr_s = (int*)alloc((size_t)E * 4);
  int* csr_t = (int*)alloc((size_t)E * 4);
  float* mean_s = (float*)alloc((size_t)NS * 128 * 4);
  float* mean_t = (float*)alloc((size_t)NT * 128 * 4);
  float* xnew_s = (float*)alloc((size_t)NS * 128 * 4);
  float* xnew_t = (float*)alloc((size_t)NT * 128 * 4);

  float* z_s = (float*)d_out;
  float* z_t = (float*)d_out + (size_t)NS * 64;

  hipMemsetAsync(cnt_s, 0, (size_t)NS * 4, stream);
  hipMemsetAsync(cnt_t, 0, (size_t)NT * 4, stream);

  const int egrid = cdiv(E, 256);
  // csr_s: destinations in S, sources in T (edge list t2s: row=t idx, col=s idx)
  count_k<<<egrid, 256, 0, stream>>>(t2s + E, E, cnt_s);
  // csr_t: destinations in T, sources in S (edge list s2t)
  count_k<<<egrid, 256, 0, stream>>>(s2t + E, E, cnt_t);

  const int nbS = cdiv(NS, 256);
  scan1_k<<<nbS, 256, 0, stream>>>(cnt_s, NS, rowptr_s, bsum);
  scan2_k<<<1, 256, 0, stream>>>(bsum, nbS, boff);
  scan3_k<<<nbS, 256, 0, stream>>>(rowptr_s, NS, boff, cursor_s, E);

  const int nbT = cdiv(NT, 256);
  scan1_k<<<nbT, 256, 0, stream>>>(cnt_t, NT, rowptr_t, bsum);
  scan2_k<<<1, 256, 0, stream>>>(bsum, nbT, boff);
  scan3_k<<<nbT, 256, 0, stream>>>(rowptr_t, NT, boff, cursor_t, E);

  fill_k<<<egrid, 256, 0, stream>>>(t2s, t2s + E, E, cursor_s, csr_s);
  fill_k<<<egrid, 256, 0, stream>>>(s2t, s2t + E, E, cursor_t, csr_t);

  // ----- layer 1 -----
  agg_mean_k<<<cdiv(NS, 4), 256, 0, stream>>>(x_t, rowptr_s, csr_s, NS, mean_s);
  agg_mean_k<<<cdiv(NT, 4), 256, 0, stream>>>(x_s, rowptr_t, csr_t, NT, mean_t);
  gemm_dual_k<128><<<cdiv(NS, 64), 256, 0, stream>>>(mean_s, x_s, W1s_l, W1s_r, b1s, xnew_s, NS);
  gemm_dual_k<128><<<cdiv(NT, 64), 256, 0, stream>>>(mean_t, x_t, W1t_l, W1t_r, b1t, xnew_t, NT);

  // ----- layer 2 (reuse mean buffers) -----
  agg_mean_k<<<cdiv(NS, 4), 256, 0, stream>>>(xnew_t, rowptr_s, csr_s, NS, mean_s);
  agg_mean_k<<<cdiv(NT, 4), 256, 0, stream>>>(xnew_s, rowptr_t, csr_t, NT, mean_t);
  gemm_dual_k<64><<<cdiv(NS, 128), 256, 0, stream>>>(mean_s, xnew_s, W2s_l, W2s_r, b2s, z_s, NS);
  gemm_dual_k<64><<<cdiv(NT, 128), 256, 0, stream>>>(mean_t, xnew_t, W2t_l, W2t_r, b2t, z_t, NT);
}

// Round 2
// 838.048 us; speedup vs baseline: 1.1707x; 1.1707x over previous
//
#include <hip/hip_runtime.h>

typedef unsigned int u32;
typedef unsigned short u16;

static inline int cdiv(int a, int b) { return (a + b - 1) / b; }

// ---------- bf16 helpers ----------
__device__ inline u32 pk_bf16(float a, float b) {
  u32 ua = __builtin_bit_cast(u32, a);
  ua += 0x7fffu + ((ua >> 16) & 1u);
  u32 ub = __builtin_bit_cast(u32, b);
  ub += 0x7fffu + ((ub >> 16) & 1u);
  return (ua >> 16) | (ub & 0xffff0000u);
}
__device__ inline float bf_lo(u32 v) { return __builtin_bit_cast(float, v << 16); }
__device__ inline float bf_hi(u32 v) { return __builtin_bit_cast(float, v & 0xffff0000u); }

// ---------- fp32 -> bf16 convert (2 elems/thread) ----------
__global__ __launch_bounds__(256) void cvt_bf16_k(const float* __restrict__ in,
                                                  u32* __restrict__ out, int n2) {
  int i = blockIdx.x * 256 + threadIdx.x;
  if (i < n2) {
    float2 v = *reinterpret_cast<const float2*>(in + (size_t)i * 2);
    out[i] = pk_bf16(v.x, v.y);
  }
}

// ---------------- CSR build ----------------

__global__ __launch_bounds__(256) void count_k(const int* __restrict__ col, int E,
                                               int* __restrict__ cnt) {
  int i = blockIdx.x * 256 + threadIdx.x;
  if (i < E) atomicAdd(&cnt[col[i]], 1);
}

__global__ __launch_bounds__(256) void scan1_k(const int* __restrict__ cnt, int n,
                                               int* __restrict__ rowptr,
                                               int* __restrict__ bsum) {
  __shared__ int sm[256];
  int t = threadIdx.x;
  int i = blockIdx.x * 256 + t;
  int v = (i < n) ? cnt[i] : 0;
  sm[t] = v;
  __syncthreads();
  for (int off = 1; off < 256; off <<= 1) {
    int x = (t >= off) ? sm[t - off] : 0;
    __syncthreads();
    if (t >= off) sm[t] += x;
    __syncthreads();
  }
  if (i < n) rowptr[i] = sm[t] - v;
  if (t == 0) bsum[blockIdx.x] = sm[255];
}

__global__ __launch_bounds__(256) void scan2_k(const int* __restrict__ bsum, int nb,
                                               int* __restrict__ boff) {
  __shared__ int sm[256];
  int t = threadIdx.x;
  int v = (t < nb) ? bsum[t] : 0;
  sm[t] = v;
  __syncthreads();
  for (int off = 1; off < 256; off <<= 1) {
    int x = (t >= off) ? sm[t - off] : 0;
    __syncthreads();
    if (t >= off) sm[t] += x;
    __syncthreads();
  }
  boff[t] = sm[t] - v;
}

__global__ __launch_bounds__(256) void scan3_k(int* __restrict__ rowptr, int n,
                                               const int* __restrict__ boff,
                                               int* __restrict__ cursor, int Etot) {
  int i = blockIdx.x * 256 + threadIdx.x;
  if (i < n) {
    int v = rowptr[i] + boff[blockIdx.x];
    rowptr[i] = v;
    cursor[i] = v;
  }
  if (i == 0) rowptr[n] = Etot;
}

__global__ __launch_bounds__(256) void fill_k(const int* __restrict__ row,
                                              const int* __restrict__ col, int E,
                                              int* __restrict__ cursor,
                                              int* __restrict__ csr) {
  int i = blockIdx.x * 256 + threadIdx.x;
  if (i < E) {
    int p = atomicAdd(&cursor[col[i]], 1);
    csr[p] = row[i];
  }
}

// ---------------- mean aggregation, 128-wide bf16 gather ----------------
// one wave per destination node; lane loads one u32 (2 bf16) => 256B/edge

__global__ __launch_bounds__(256) void agg128_k(const u16* __restrict__ xsrc,
                                                const int* __restrict__ rowptr,
                                                const int* __restrict__ csr, int n_dst,
                                                float* __restrict__ outm) {
  int node = blockIdx.x * 4 + (threadIdx.x >> 6);
  if (node >= n_dst) return;
  int lane = threadIdx.x & 63;
  int s = rowptr[node], e = rowptr[node + 1];
  float ax = 0.f, ay = 0.f;
  int i = s;
  for (; i + 4 <= e; i += 4) {
    int i0 = csr[i], i1 = csr[i + 1], i2 = csr[i + 2], i3 = csr[i + 3];
    u32 v0 = *reinterpret_cast<const u32*>(xsrc + (size_t)i0 * 128 + lane * 2);
    u32 v1 = *reinterpret_cast<const u32*>(xsrc + (size_t)i1 * 128 + lane * 2);
    u32 v2 = *reinterpret_cast<const u32*>(xsrc + (size_t)i2 * 128 + lane * 2);
    u32 v3 = *reinterpret_cast<const u32*>(xsrc + (size_t)i3 * 128 + lane * 2);
    ax += (bf_lo(v0) + bf_lo(v1)) + (bf_lo(v2) + bf_lo(v3));
    ay += (bf_hi(v0) + bf_hi(v1)) + (bf_hi(v2) + bf_hi(v3));
  }
  for (; i < e; ++i) {
    u32 v0 = *reinterpret_cast<const u32*>(xsrc + (size_t)csr[i] * 128 + lane * 2);
    ax += bf_lo(v0);
    ay += bf_hi(v0);
  }
  float inv = (e > s) ? 1.f / (float)(e - s) : 0.f;
  float2 r;
  r.x = ax * inv;
  r.y = ay * inv;
  *reinterpret_cast<float2*>(outm + (size_t)node * 128 + lane * 2) = r;
}

// ---------------- mean aggregation, 64-wide bf16 gather + epilogue ----------------
// one wave per node, 2 edges in flight (lane>>5), 32 feature-lanes x 2 bf16
// z = mean(h[src]) + g[node] + bias

__global__ __launch_bounds__(256) void agg64_epi_k(const u16* __restrict__ h,
                                                   const int* __restrict__ rowptr,
                                                   const int* __restrict__ csr, int n_dst,
                                                   const float* __restrict__ g,
                                                   const float* __restrict__ bias,
                                                   float* __restrict__ z) {
  int node = blockIdx.x * 4 + (threadIdx.x >> 6);
  if (node >= n_dst) return;
  int lane = threadIdx.x & 63;
  int half = lane >> 5;
  int fl = lane & 31;
  int s = rowptr[node], e = rowptr[node + 1];
  float ax = 0.f, ay = 0.f;
  int i = s + half;
  for (; i + 2 < e; i += 4) {
    int i0 = csr[i], i1 = csr[i + 2];
    u32 v0 = *reinterpret_cast<const u32*>(h + (size_t)i0 * 64 + fl * 2);
    u32 v1 = *reinterpret_cast<const u32*>(h + (size_t)i1 * 64 + fl * 2);
    ax += bf_lo(v0) + bf_lo(v1);
    ay += bf_hi(v0) + bf_hi(v1);
  }
  for (; i < e; i += 2) {
    u32 v0 = *reinterpret_cast<const u32*>(h + (size_t)csr[i] * 64 + fl * 2);
    ax += bf_lo(v0);
    ay += bf_hi(v0);
  }
  ax += __shfl_xor(ax, 32);
  ay += __shfl_xor(ay, 32);
  if (lane < 32) {
    float inv = (e > s) ? 1.f / (float)(e - s) : 0.f;
    float2 gv = *reinterpret_cast<const float2*>(g + (size_t)node * 64 + fl * 2);
    float2 bv = *reinterpret_cast<const float2*>(bias + fl * 2);
    float2 r;
    r.x = ax * inv + gv.x + bv.x;
    r.y = ay * inv + gv.y + bv.y;
    *reinterpret_cast<float2*>(z + (size_t)node * 64 + fl * 2) = r;
  }
}

// ---------------- layer-1 fused dual GEMM: out = A0@W0 + A1@W1 + bias ----------------
// A0,A1: [M][128], W0,W1: [128][128], out fp32 [M][128]

__global__ __launch_bounds__(256) void gemm_l1_k(const float* __restrict__ A0,
                                                 const float* __restrict__ A1,
                                                 const float* __restrict__ W0,
                                                 const float* __restrict__ W1,
                                                 const float* __restrict__ bias,
                                                 float* __restrict__ out, int M) {
  constexpr int ROWS = 64, KC = 32;
  __shared__ float Alds[ROWS][KC + 1];
  __shared__ float Wlds[KC][128];

  const int tid = threadIdx.x;
  const int tx = tid % 16;
  const int ty = tid / 16;
  const int c0 = tx * 8;
  const int r0 = ty * 4;
  const int rowBase = blockIdx.x * ROWS;

  float acc[4][8];
#pragma unroll
  for (int i = 0; i < 4; ++i)
#pragma unroll
    for (int j = 0; j < 8; ++j) acc[i][j] = 0.f;

  for (int kc = 0; kc < 8; ++kc) {
    const float* Asrc = (kc < 4) ? A0 : A1;
    const float* Wsrc = (kc < 4) ? W0 : W1;
    const int kbase = (kc & 3) * KC;
#pragma unroll
    for (int it = 0; it < 2; ++it) {
      int idx = it * 256 + tid;
      int rr = idx / 8;
      int kk = (idx % 8) * 4;
      int gr = rowBase + rr;
      float4 v = make_float4(0.f, 0.f, 0.f, 0.f);
      if (gr < M) v = *reinterpret_cast<const float4*>(Asrc + (size_t)gr * 128 + kbase + kk);
      Alds[rr][kk + 0] = v.x;
      Alds[rr][kk + 1] = v.y;
      Alds[rr][kk + 2] = v.z;
      Alds[rr][kk + 3] = v.w;
    }
#pragma unroll
    for (int it = 0; it < 4; ++it) {
      int idx = it * 256 + tid;
      int kk = idx / 32;
      int cc = (idx % 32) * 4;
      float4 v = *reinterpret_cast<const float4*>(Wsrc + (size_t)(kbase + kk) * 128 + cc);
      *reinterpret_cast<float4*>(&Wlds[kk][cc]) = v;
    }
    __syncthreads();
#pragma unroll
    for (int k = 0; k < KC; ++k) {
      float a0 = Alds[r0 + 0][k];
      float a1 = Alds[r0 + 1][k];
      float a2 = Alds[r0 + 2][k];
      float a3 = Alds[r0 + 3][k];
      const float4 w0 = *reinterpret_cast<const float4*>(&Wlds[k][c0]);
      const float4 w1 = *reinterpret_cast<const float4*>(&Wlds[k][c0 + 4]);
      acc[0][0] += a0 * w0.x; acc[0][1] += a0 * w0.y; acc[0][2] += a0 * w0.z; acc[0][3] += a0 * w0.w;
      acc[0][4] += a0 * w1.x; acc[0][5] += a0 * w1.y; acc[0][6] += a0 * w1.z; acc[0][7] += a0 * w1.w;
      acc[1][0] += a1 * w0.x; acc[1][1] += a1 * w0.y; acc[1][2] += a1 * w0.z; acc[1][3] += a1 * w0.w;
      acc[1][4] += a1 * w1.x; acc[1][5] += a1 * w1.y; acc[1][6] += a1 * w1.z; acc[1][7] += a1 * w1.w;
      acc[2][0] += a2 * w0.x; acc[2][1] += a2 * w0.y; acc[2][2] += a2 * w0.z; acc[2][3] += a2 * w0.w;
      acc[2][4] += a2 * w1.x; acc[2][5] += a2 * w1.y; acc[2][6] += a2 * w1.z; acc[2][7] += a2 * w1.w;
      acc[3][0] += a3 * w0.x; acc[3][1] += a3 * w0.y; acc[3][2] += a3 * w0.z; acc[3][3] += a3 * w0.w;
      acc[3][4] += a3 * w1.x; acc[3][5] += a3 * w1.y; acc[3][6] += a3 * w1.z; acc[3][7] += a3 * w1.w;
    }
    __syncthreads();
  }

  float b[8];
#pragma unroll
  for (int j = 0; j < 8; ++j) b[j] = bias[c0 + j];
#pragma unroll
  for (int i = 0; i < 4; ++i) {
    int gr = rowBase + r0 + i;
    if (gr < M) {
      float4 v0, v1;
      v0.x = acc[i][0] + b[0]; v0.y = acc[i][1] + b[1];
      v0.z = acc[i][2] + b[2]; v0.w = acc[i][3] + b[3];
      v1.x = acc[i][4] + b[4]; v1.y = acc[i][5] + b[5];
      v1.z = acc[i][6] + b[6]; v1.w = acc[i][7] + b[7];
      *reinterpret_cast<float4*>(out + (size_t)gr * 128 + c0) = v0;
      *reinterpret_cast<float4*>(out + (size_t)gr * 128 + c0 + 4) = v1;
    }
  }
}

// ---------------- layer-2 fused GEMM: [h | g] = X @ [Wa | Wb] ----------------
// X: [M][128], Wa,Wb: [128][64]; h bf16 [M][64], g fp32 [M][64]; no bias.

__global__ __launch_bounds__(256) void gemm_l2_k(const float* __restrict__ X,
                                                 const float* __restrict__ Wa,
                                                 const float* __restrict__ Wb,
                                                 u16* __restrict__ h,
                                                 float* __restrict__ g, int M) {
  constexpr int ROWS = 64, KC = 32;
  __shared__ float Alds[ROWS][KC + 1];
  __shared__ float Wlds[KC][128];

  const int tid = threadIdx.x;
  const int tx = tid % 16;
  const int ty = tid / 16;
  const int c0 = tx * 8;
  const int r0 = ty * 4;
  const int rowBase = blockIdx.x * ROWS;

  float acc[4][8];
#pragma unroll
  for (int i = 0; i < 4; ++i)
#pragma unroll
    for (int j = 0; j < 8; ++j) acc[i][j] = 0.f;

  for (int kc = 0; kc < 4; ++kc) {
    const int kbase = kc * KC;
#pragma unroll
    for (int it = 0; it < 2; ++it) {
      int idx = it * 256 + tid;
      int rr = idx / 8;
      int kk = (idx % 8) * 4;
      int gr = rowBase + rr;
      float4 v = make_float4(0.f, 0.f, 0.f, 0.f);
      if (gr < M) v = *reinterpret_cast<const float4*>(X + (size_t)gr * 128 + kbase + kk);
      Alds[rr][kk + 0] = v.x;
      Alds[rr][kk + 1] = v.y;
      Alds[rr][kk + 2] = v.z;
      Alds[rr][kk + 3] = v.w;
    }
#pragma unroll
    for (int it = 0; it < 4; ++it) {
      int idx = it * 256 + tid;
      int kk = idx / 32;
      int cc = (idx % 32) * 4;
      const float* src = (cc < 64) ? (Wa + (size_t)(kbase + kk) * 64 + cc)
                                   : (Wb + (size_t)(kbase + kk) * 64 + (cc - 64));
      float4 v = *reinterpret_cast<const float4*>(src);
      *reinterpret_cast<float4*>(&Wlds[kk][cc]) = v;
    }
    __syncthreads();
#pragma unroll
    for (int k = 0; k < KC; ++k) {
      float a0 = Alds[r0 + 0][k];
      float a1 = Alds[r0 + 1][k];
      float a2 = Alds[r0 + 2][k];
      float a3 = Alds[r0 + 3][k];
      const float4 w0 = *reinterpret_cast<const float4*>(&Wlds[k][c0]);
      const float4 w1 = *reinterpret_cast<const float4*>(&Wlds[k][c0 + 4]);
      acc[0][0] += a0 * w0.x; acc[0][1] += a0 * w0.y; acc[0][2] += a0 * w0.z; acc[0][3] += a0 * w0.w;
      acc[0][4] += a0 * w1.x; acc[0][5] += a0 * w1.y; acc[0][6] += a0 * w1.z; acc[0][7] += a0 * w1.w;
      acc[1][0] += a1 * w0.x; acc[1][1] += a1 * w0.y; acc[1][2] += a1 * w0.z; acc[1][3] += a1 * w0.w;
      acc[1][4] += a1 * w1.x; acc[1][5] += a1 * w1.y; acc[1][6] += a1 * w1.z; acc[1][7] += a1 * w1.w;
      acc[2][0] += a2 * w0.x; acc[2][1] += a2 * w0.y; acc[2][2] += a2 * w0.z; acc[2][3] += a2 * w0.w;
      acc[2][4] += a2 * w1.x; acc[2][5] += a2 * w1.y; acc[2][6] += a2 * w1.z; acc[2][7] += a2 * w1.w;
      acc[3][0] += a3 * w0.x; acc[3][1] += a3 * w0.y; acc[3][2] += a3 * w0.z; acc[3][3] += a3 * w0.w;
      acc[3][4] += a3 * w1.x; acc[3][5] += a3 * w1.y; acc[3][6] += a3 * w1.z; acc[3][7] += a3 * w1.w;
    }
    __syncthreads();
  }

  if (c0 < 64) {
#pragma unroll
    for (int i = 0; i < 4; ++i) {
      int gr = rowBase + r0 + i;
      if (gr < M) {
        uint4 p;
        p.x = pk_bf16(acc[i][0], acc[i][1]);
        p.y = pk_bf16(acc[i][2], acc[i][3]);
        p.z = pk_bf16(acc[i][4], acc[i][5]);
        p.w = pk_bf16(acc[i][6], acc[i][7]);
        *reinterpret_cast<uint4*>(h + (size_t)gr * 64 + c0) = p;
      }
    }
  } else {
    int cg = c0 - 64;
#pragma unroll
    for (int i = 0; i < 4; ++i) {
      int gr = rowBase + r0 + i;
      if (gr < M) {
        float4 v0, v1;
        v0.x = acc[i][0]; v0.y = acc[i][1]; v0.z = acc[i][2]; v0.w = acc[i][3];
        v1.x = acc[i][4]; v1.y = acc[i][5]; v1.z = acc[i][6]; v1.w = acc[i][7];
        *reinterpret_cast<float4*>(g + (size_t)gr * 64 + cg) = v0;
        *reinterpret_cast<float4*>(g + (size_t)gr * 64 + cg + 4) = v1;
      }
    }
  }
}

// ---------------- launch ----------------

extern "C" void kernel_launch(void* const* d_in, const int* in_sizes, int n_in,
                              void* d_out, int out_size, void* d_ws, size_t ws_size,
                              hipStream_t stream) {
  const float* x_s = (const float*)d_in[0];
  const float* x_t = (const float*)d_in[1];
  const int* s2t = (const int*)d_in[2];
  const int* t2s = (const int*)d_in[3];
  const float* W1s_l = (const float*)d_in[4];
  const float* W1s_r = (const float*)d_in[5];
  const float* b1s = (const float*)d_in[6];
  const float* W1t_l = (const float*)d_in[7];
  const float* W1t_r = (const float*)d_in[8];
  const float* b1t = (const float*)d_in[9];
  const float* W2s_l = (const float*)d_in[10];
  const float* W2s_r = (const float*)d_in[11];
  const float* b2s = (const float*)d_in[12];
  const float* W2t_l = (const float*)d_in[13];
  const float* W2t_r = (const float*)d_in[14];
  const float* b2t = (const float*)d_in[15];

  const int NS = in_sizes[0] / 128;
  const int NT = in_sizes[1] / 128;
  const int E = in_sizes[2] / 2;

  char* ws = (char*)d_ws;
  size_t off = 0;
  auto alloc = [&](size_t bytes) -> void* {
    void* p = ws + off;
    off = (off + bytes + 255) & ~(size_t)255;
    return p;
  };

  int* cnt_s = (int*)alloc((size_t)NS * 4);
  int* cnt_t = (int*)alloc((size_t)NT * 4);
  int* rowptr_s = (int*)alloc((size_t)(NS + 1) * 4);
  int* rowptr_t = (int*)alloc((size_t)(NT + 1) * 4);
  int* cursor_s = (int*)alloc((size_t)NS * 4);
  int* cursor_t = (int*)alloc((size_t)NT * 4);
  int* bsum = (int*)alloc(256 * 4);
  int* boff = (int*)alloc(256 * 4);
  int* csr_s = (int*)alloc((size_t)E * 4);
  int* csr_t = (int*)alloc((size_t)E * 4);

  // R2: mean_s|mean_t  ->  later h_s,h_t,g_s,g_t
  char* R2 = (char*)alloc((size_t)(NS + NT) * 128 * 4);
  // R3: xs_bf|xt_bf    ->  later xnew_s|xnew_t
  char* R3 = (char*)alloc((size_t)(NS + NT) * 128 * 4);

  float* mean_s = (float*)R2;
  float* mean_t = mean_s + (size_t)NS * 128;
  u16* h_s = (u16*)R2;
  u16* h_t = h_s + (size_t)NS * 64;
  float* g_s = (float*)(h_t + (size_t)NT * 64);
  float* g_t = g_s + (size_t)NS * 64;

  u16* xs_bf = (u16*)R3;
  u16* xt_bf = xs_bf + (size_t)NS * 128;
  float* xnew_s = (float*)R3;
  float* xnew_t = xnew_s + (size_t)NS * 128;

  float* z_s = (float*)d_out;
  float* z_t = (float*)d_out + (size_t)NS * 64;

  hipMemsetAsync(cnt_s, 0, (size_t)NS * 4, stream);
  hipMemsetAsync(cnt_t, 0, (size_t)NT * 4, stream);

  // fp32 -> bf16 feature copies
  cvt_bf16_k<<<cdiv(NS * 64, 256), 256, 0, stream>>>(x_s, (u32*)xs_bf, NS * 64);
  cvt_bf16_k<<<cdiv(NT * 64, 256), 256, 0, stream>>>(x_t, (u32*)xt_bf, NT * 64);

  const int egrid = cdiv(E, 256);
  count_k<<<egrid, 256, 0, stream>>>(t2s + E, E, cnt_s);
  count_k<<<egrid, 256, 0, stream>>>(s2t + E, E, cnt_t);

  const int nbS = cdiv(NS, 256);
  scan1_k<<<nbS, 256, 0, stream>>>(cnt_s, NS, rowptr_s, bsum);
  scan2_k<<<1, 256, 0, stream>>>(bsum, nbS, boff);
  scan3_k<<<nbS, 256, 0, stream>>>(rowptr_s, NS, boff, cursor_s, E);

  const int nbT = cdiv(NT, 256);
  scan1_k<<<nbT, 256, 0, stream>>>(cnt_t, NT, rowptr_t, bsum);
  scan2_k<<<1, 256, 0, stream>>>(bsum, nbT, boff);
  scan3_k<<<nbT, 256, 0, stream>>>(rowptr_t, NT, boff, cursor_t, E);

  fill_k<<<egrid, 256, 0, stream>>>(t2s, t2s + E, E, cursor_s, csr_s);
  fill_k<<<egrid, 256, 0, stream>>>(s2t, s2t + E, E, cursor_t, csr_t);

  // ----- layer 1 -----
  agg128_k<<<cdiv(NS, 4), 256, 0, stream>>>(xt_bf, rowptr_s, csr_s, NS, mean_s);
  agg128_k<<<cdiv(NT, 4), 256, 0, stream>>>(xs_bf, rowptr_t, csr_t, NT, mean_t);
  gemm_l1_k<<<cdiv(NS, 64), 256, 0, stream>>>(mean_s, x_s, W1s_l, W1s_r, b1s, xnew_s, NS);
  gemm_l1_k<<<cdiv(NT, 64), 256, 0, stream>>>(mean_t, x_t, W1t_l, W1t_r, b1t, xnew_t, NT);

  // ----- layer 2 (transform-first) -----
  // h_s = xnew_s @ W2t_l (feeds z_t), g_s = xnew_s @ W2s_r (dst term of z_s)
  gemm_l2_k<<<cdiv(NS, 64), 256, 0, stream>>>(xnew_s, W2t_l, W2s_r, h_s, g_s, NS);
  // h_t = xnew_t @ W2s_l (feeds z_s), g_t = xnew_t @ W2t_r (dst term of z_t)
  gemm_l2_k<<<cdiv(NT, 64), 256, 0, stream>>>(xnew_t, W2s_l, W2t_r, h_t, g_t, NT);

  agg64_epi_k<<<cdiv(NS, 4), 256, 0, stream>>>(h_t, rowptr_s, csr_s, NS, g_s, b2s, z_s);
  agg64_epi_k<<<cdiv(NT, 4), 256, 0, stream>>>(h_s, rowptr_t, csr_t, NT, g_t, b2t, z_t);
}

// Round 3
// 516.747 us; speedup vs baseline: 1.8987x; 1.6218x over previous
//
#include <hip/hip_runtime.h>

typedef unsigned int u32;
typedef unsigned short u16;

static inline int cdiv(int a, int b) { return (a + b - 1) / b; }

#define NBKT 512   // buckets = dst >> BSHIFT
#define BSHIFT 7   // 128 nodes per bucket
#define BNODES 128
#define EPB 4096   // edges per block for hist/scatter

// ---------- bf16 helpers ----------
__device__ inline u32 pk_bf16(float a, float b) {
  u32 ua = __builtin_bit_cast(u32, a);
  ua += 0x7fffu + ((ua >> 16) & 1u);
  u32 ub = __builtin_bit_cast(u32, b);
  ub += 0x7fffu + ((ub >> 16) & 1u);
  return (ua >> 16) | (ub & 0xffff0000u);
}
__device__ inline float bf_lo(u32 v) { return __builtin_bit_cast(float, v << 16); }
__device__ inline float bf_hi(u32 v) { return __builtin_bit_cast(float, v & 0xffff0000u); }

// ---------- fp32 -> bf16 convert (2 elems/thread) ----------
__global__ __launch_bounds__(256) void cvt_bf16_k(const float* __restrict__ in,
                                                  u32* __restrict__ out, int n2) {
  int i = blockIdx.x * 256 + threadIdx.x;
  if (i < n2) {
    float2 v = *reinterpret_cast<const float2*>(in + (size_t)i * 2);
    out[i] = pk_bf16(v.x, v.y);
  }
}

// ================= CSR build via bucketed counting sort =================

// per-block bucket histogram -> H[blk][NBKT]
__global__ __launch_bounds__(256) void hist_k(const int* __restrict__ col, int E,
                                              int* __restrict__ H) {
  __shared__ int h[NBKT];
  int t = threadIdx.x;
  for (int i = t; i < NBKT; i += 256) h[i] = 0;
  __syncthreads();
  int base = blockIdx.x * EPB;
  int end = min(base + EPB, E);
  for (int i = base + t; i < end; i += 256) atomicAdd(&h[col[i] >> BSHIFT], 1);
  __syncthreads();
  int* Hrow = H + (size_t)blockIdx.x * NBKT;
  for (int i = t; i < NBKT; i += 256) Hrow[i] = h[i];
}

// one wave per bucket: H[:,b] -> exclusive prefix over blocks (in place); tot[b] = sum
__global__ __launch_bounds__(64) void scanH_k(int* __restrict__ H, int nblk,
                                              int* __restrict__ tot) {
  int b = blockIdx.x;
  int lane = threadIdx.x;
  int carry = 0;
  for (int c = 0; c < nblk; c += 64) {
    int idx = c + lane;
    int v = (idx < nblk) ? H[(size_t)idx * NBKT + b] : 0;
    int s = v;
#pragma unroll
    for (int off = 1; off < 64; off <<= 1) {
      int x = __shfl_up(s, off);
      if (lane >= off) s += x;
    }
    if (idx < nblk) H[(size_t)idx * NBKT + b] = s - v + carry;
    carry += __shfl(s, 63);
  }
  if (lane == 0) tot[b] = carry;
}

// single block: exclusive scan of tot[NBKT] -> basep[NBKT], basep[NBKT] = E
__global__ __launch_bounds__(NBKT) void baseScan_k(const int* __restrict__ tot,
                                                   int* __restrict__ basep, int E) {
  __shared__ int sm[NBKT];
  int t = threadIdx.x;
  int v = tot[t];
  sm[t] = v;
  __syncthreads();
  for (int off = 1; off < NBKT; off <<= 1) {
    int x = (t >= off) ? sm[t - off] : 0;
    __syncthreads();
    if (t >= off) sm[t] += x;
    __syncthreads();
  }
  basep[t] = sm[t] - v;
  if (t == NBKT - 1) basep[NBKT] = E;
}

// scatter (src,dst) pairs into bucket-contiguous staging
__global__ __launch_bounds__(256) void scatter_k(const int* __restrict__ row,
                                                 const int* __restrict__ col, int E,
                                                 const int* __restrict__ H,
                                                 const int* __restrict__ basep,
                                                 int2* __restrict__ bkt) {
  __shared__ int cur[NBKT];
  int t = threadIdx.x;
  const int* Hrow = H + (size_t)blockIdx.x * NBKT;
  for (int i = t; i < NBKT; i += 256) cur[i] = basep[i] + Hrow[i];
  __syncthreads();
  int base = blockIdx.x * EPB;
  int end = min(base + EPB, E);
  for (int i = base + t; i < end; i += 256) {
    int c = col[i];
    int p = atomicAdd(&cur[c >> BSHIFT], 1);
    bkt[p] = make_int2(row[i], c);
  }
}

// one block per bucket: per-node counts, rowptr, and csr fill (L2-local region)
__global__ __launch_bounds__(256) void finalize_k(const int2* __restrict__ bkt,
                                                  const int* __restrict__ basep,
                                                  int N, int Etot,
                                                  int* __restrict__ rowptr,
                                                  int* __restrict__ csr) {
  __shared__ int cnt[BNODES];
  __shared__ int excl[BNODES];
  int b = blockIdx.x;
  int t = threadIdx.x;
  int node0 = b << BSHIFT;
  int rs = basep[b], re = basep[b + 1];
  if (t < BNODES) cnt[t] = 0;
  __syncthreads();
  for (int i = rs + t; i < re; i += 256) {
    int2 p = bkt[i];
    atomicAdd(&cnt[p.y - node0], 1);
  }
  __syncthreads();
  if (t < BNODES) excl[t] = cnt[t];
  __syncthreads();
  for (int off = 1; off < BNODES; off <<= 1) {
    int x = 0;
    if (t < BNODES && t >= off) x = excl[t - off];
    __syncthreads();
    if (t < BNODES && t >= off) excl[t] += x;
    __syncthreads();
  }
  if (t < BNODES) {
    int node = node0 + t;
    int start = rs + excl[t] - cnt[t];   // exclusive
    if (node < N) rowptr[node] = start;
    cnt[t] = start;                      // becomes cursor
  }
  if (b == 0 && t == 0) rowptr[N] = Etot;
  __syncthreads();
  for (int i = rs + t; i < re; i += 256) {
    int2 p = bkt[i];
    int pos = atomicAdd(&cnt[p.y - node0], 1);
    csr[pos] = p.x;
  }
}

// ---------------- mean aggregation, 128-wide bf16 gather ----------------

__global__ __launch_bounds__(256) void agg128_k(const u16* __restrict__ xsrc,
                                                const int* __restrict__ rowptr,
                                                const int* __restrict__ csr, int n_dst,
                                                float* __restrict__ outm) {
  int node = blockIdx.x * 4 + (threadIdx.x >> 6);
  if (node >= n_dst) return;
  int lane = threadIdx.x & 63;
  int s = rowptr[node], e = rowptr[node + 1];
  float ax = 0.f, ay = 0.f;
  int i = s;
  for (; i + 4 <= e; i += 4) {
    int i0 = csr[i], i1 = csr[i + 1], i2 = csr[i + 2], i3 = csr[i + 3];
    u32 v0 = *reinterpret_cast<const u32*>(xsrc + (size_t)i0 * 128 + lane * 2);
    u32 v1 = *reinterpret_cast<const u32*>(xsrc + (size_t)i1 * 128 + lane * 2);
    u32 v2 = *reinterpret_cast<const u32*>(xsrc + (size_t)i2 * 128 + lane * 2);
    u32 v3 = *reinterpret_cast<const u32*>(xsrc + (size_t)i3 * 128 + lane * 2);
    ax += (bf_lo(v0) + bf_lo(v1)) + (bf_lo(v2) + bf_lo(v3));
    ay += (bf_hi(v0) + bf_hi(v1)) + (bf_hi(v2) + bf_hi(v3));
  }
  for (; i < e; ++i) {
    u32 v0 = *reinterpret_cast<const u32*>(xsrc + (size_t)csr[i] * 128 + lane * 2);
    ax += bf_lo(v0);
    ay += bf_hi(v0);
  }
  float inv = (e > s) ? 1.f / (float)(e - s) : 0.f;
  float2 r;
  r.x = ax * inv;
  r.y = ay * inv;
  *reinterpret_cast<float2*>(outm + (size_t)node * 128 + lane * 2) = r;
}

// ---------------- mean aggregation, 64-wide bf16 gather + epilogue ----------------

__global__ __launch_bounds__(256) void agg64_epi_k(const u16* __restrict__ h,
                                                   const int* __restrict__ rowptr,
                                                   const int* __restrict__ csr, int n_dst,
                                                   const float* __restrict__ g,
                                                   const float* __restrict__ bias,
                                                   float* __restrict__ z) {
  int node = blockIdx.x * 4 + (threadIdx.x >> 6);
  if (node >= n_dst) return;
  int lane = threadIdx.x & 63;
  int half = lane >> 5;
  int fl = lane & 31;
  int s = rowptr[node], e = rowptr[node + 1];
  float ax = 0.f, ay = 0.f;
  int i = s + half;
  for (; i + 2 < e; i += 4) {
    int i0 = csr[i], i1 = csr[i + 2];
    u32 v0 = *reinterpret_cast<const u32*>(h + (size_t)i0 * 64 + fl * 2);
    u32 v1 = *reinterpret_cast<const u32*>(h + (size_t)i1 * 64 + fl * 2);
    ax += bf_lo(v0) + bf_lo(v1);
    ay += bf_hi(v0) + bf_hi(v1);
  }
  for (; i < e; i += 2) {
    u32 v0 = *reinterpret_cast<const u32*>(h + (size_t)csr[i] * 64 + fl * 2);
    ax += bf_lo(v0);
    ay += bf_hi(v0);
  }
  ax += __shfl_xor(ax, 32);
  ay += __shfl_xor(ay, 32);
  if (lane < 32) {
    float inv = (e > s) ? 1.f / (float)(e - s) : 0.f;
    float2 gv = *reinterpret_cast<const float2*>(g + (size_t)node * 64 + fl * 2);
    float2 bv = *reinterpret_cast<const float2*>(bias + fl * 2);
    float2 r;
    r.x = ax * inv + gv.x + bv.x;
    r.y = ay * inv + gv.y + bv.y;
    *reinterpret_cast<float2*>(z + (size_t)node * 64 + fl * 2) = r;
  }
}

// ---------------- layer-1 fused dual GEMM: out = A0@W0 + A1@W1 + bias ----------------

__global__ __launch_bounds__(256) void gemm_l1_k(const float* __restrict__ A0,
                                                 const float* __restrict__ A1,
                                                 const float* __restrict__ W0,
                                                 const float* __restrict__ W1,
                                                 const float* __restrict__ bias,
                                                 float* __restrict__ out, int M) {
  constexpr int ROWS = 64, KC = 32;
  __shared__ float Alds[ROWS][KC + 1];
  __shared__ float Wlds[KC][128];

  const int tid = threadIdx.x;
  const int tx = tid % 16;
  const int ty = tid / 16;
  const int c0 = tx * 8;
  const int r0 = ty * 4;
  const int rowBase = blockIdx.x * ROWS;

  float acc[4][8];
#pragma unroll
  for (int i = 0; i < 4; ++i)
#pragma unroll
    for (int j = 0; j < 8; ++j) acc[i][j] = 0.f;

  for (int kc = 0; kc < 8; ++kc) {
    const float* Asrc = (kc < 4) ? A0 : A1;
    const float* Wsrc = (kc < 4) ? W0 : W1;
    const int kbase = (kc & 3) * KC;
#pragma unroll
    for (int it = 0; it < 2; ++it) {
      int idx = it * 256 + tid;
      int rr = idx / 8;
      int kk = (idx % 8) * 4;
      int gr = rowBase + rr;
      float4 v = make_float4(0.f, 0.f, 0.f, 0.f);
      if (gr < M) v = *reinterpret_cast<const float4*>(Asrc + (size_t)gr * 128 + kbase + kk);
      Alds[rr][kk + 0] = v.x;
      Alds[rr][kk + 1] = v.y;
      Alds[rr][kk + 2] = v.z;
      Alds[rr][kk + 3] = v.w;
    }
#pragma unroll
    for (int it = 0; it < 4; ++it) {
      int idx = it * 256 + tid;
      int kk = idx / 32;
      int cc = (idx % 32) * 4;
      float4 v = *reinterpret_cast<const float4*>(Wsrc + (size_t)(kbase + kk) * 128 + cc);
      *reinterpret_cast<float4*>(&Wlds[kk][cc]) = v;
    }
    __syncthreads();
#pragma unroll
    for (int k = 0; k < KC; ++k) {
      float a0 = Alds[r0 + 0][k];
      float a1 = Alds[r0 + 1][k];
      float a2 = Alds[r0 + 2][k];
      float a3 = Alds[r0 + 3][k];
      const float4 w0 = *reinterpret_cast<const float4*>(&Wlds[k][c0]);
      const float4 w1 = *reinterpret_cast<const float4*>(&Wlds[k][c0 + 4]);
      acc[0][0] += a0 * w0.x; acc[0][1] += a0 * w0.y; acc[0][2] += a0 * w0.z; acc[0][3] += a0 * w0.w;
      acc[0][4] += a0 * w1.x; acc[0][5] += a0 * w1.y; acc[0][6] += a0 * w1.z; acc[0][7] += a0 * w1.w;
      acc[1][0] += a1 * w0.x; acc[1][1] += a1 * w0.y; acc[1][2] += a1 * w0.z; acc[1][3] += a1 * w0.w;
      acc[1][4] += a1 * w1.x; acc[1][5] += a1 * w1.y; acc[1][6] += a1 * w1.z; acc[1][7] += a1 * w1.w;
      acc[2][0] += a2 * w0.x; acc[2][1] += a2 * w0.y; acc[2][2] += a2 * w0.z; acc[2][3] += a2 * w0.w;
      acc[2][4] += a2 * w1.x; acc[2][5] += a2 * w1.y; acc[2][6] += a2 * w1.z; acc[2][7] += a2 * w1.w;
      acc[3][0] += a3 * w0.x; acc[3][1] += a3 * w0.y; acc[3][2] += a3 * w0.z; acc[3][3] += a3 * w0.w;
      acc[3][4] += a3 * w1.x; acc[3][5] += a3 * w1.y; acc[3][6] += a3 * w1.z; acc[3][7] += a3 * w1.w;
    }
    __syncthreads();
  }

  float b[8];
#pragma unroll
  for (int j = 0; j < 8; ++j) b[j] = bias[c0 + j];
#pragma unroll
  for (int i = 0; i < 4; ++i) {
    int gr = rowBase + r0 + i;
    if (gr < M) {
      float4 v0, v1;
      v0.x = acc[i][0] + b[0]; v0.y = acc[i][1] + b[1];
      v0.z = acc[i][2] + b[2]; v0.w = acc[i][3] + b[3];
      v1.x = acc[i][4] + b[4]; v1.y = acc[i][5] + b[5];
      v1.z = acc[i][6] + b[6]; v1.w = acc[i][7] + b[7];
      *reinterpret_cast<float4*>(out + (size_t)gr * 128 + c0) = v0;
      *reinterpret_cast<float4*>(out + (size_t)gr * 128 + c0 + 4) = v1;
    }
  }
}

// ---------------- layer-2 fused GEMM: [h | g] = X @ [Wa | Wb] ----------------

__global__ __launch_bounds__(256) void gemm_l2_k(const float* __restrict__ X,
                                                 const float* __restrict__ Wa,
                                                 const float* __restrict__ Wb,
                                                 u16* __restrict__ h,
                                                 float* __restrict__ g, int M) {
  constexpr int ROWS = 64, KC = 32;
  __shared__ float Alds[ROWS][KC + 1];
  __shared__ float Wlds[KC][128];

  const int tid = threadIdx.x;
  const int tx = tid % 16;
  const int ty = tid / 16;
  const int c0 = tx * 8;
  const int r0 = ty * 4;
  const int rowBase = blockIdx.x * ROWS;

  float acc[4][8];
#pragma unroll
  for (int i = 0; i < 4; ++i)
#pragma unroll
    for (int j = 0; j < 8; ++j) acc[i][j] = 0.f;

  for (int kc = 0; kc < 4; ++kc) {
    const int kbase = kc * KC;
#pragma unroll
    for (int it = 0; it < 2; ++it) {
      int idx = it * 256 + tid;
      int rr = idx / 8;
      int kk = (idx % 8) * 4;
      int gr = rowBase + rr;
      float4 v = make_float4(0.f, 0.f, 0.f, 0.f);
      if (gr < M) v = *reinterpret_cast<const float4*>(X + (size_t)gr * 128 + kbase + kk);
      Alds[rr][kk + 0] = v.x;
      Alds[rr][kk + 1] = v.y;
      Alds[rr][kk + 2] = v.z;
      Alds[rr][kk + 3] = v.w;
    }
#pragma unroll
    for (int it = 0; it < 4; ++it) {
      int idx = it * 256 + tid;
      int kk = idx / 32;
      int cc = (idx % 32) * 4;
      const float* src = (cc < 64) ? (Wa + (size_t)(kbase + kk) * 64 + cc)
                                   : (Wb + (size_t)(kbase + kk) * 64 + (cc - 64));
      float4 v = *reinterpret_cast<const float4*>(src);
      *reinterpret_cast<float4*>(&Wlds[kk][cc]) = v;
    }
    __syncthreads();
#pragma unroll
    for (int k = 0; k < KC; ++k) {
      float a0 = Alds[r0 + 0][k];
      float a1 = Alds[r0 + 1][k];
      float a2 = Alds[r0 + 2][k];
      float a3 = Alds[r0 + 3][k];
      const float4 w0 = *reinterpret_cast<const float4*>(&Wlds[k][c0]);
      const float4 w1 = *reinterpret_cast<const float4*>(&Wlds[k][c0 + 4]);
      acc[0][0] += a0 * w0.x; acc[0][1] += a0 * w0.y; acc[0][2] += a0 * w0.z; acc[0][3] += a0 * w0.w;
      acc[0][4] += a0 * w1.x; acc[0][5] += a0 * w1.y; acc[0][6] += a0 * w1.z; acc[0][7] += a0 * w1.w;
      acc[1][0] += a1 * w0.x; acc[1][1] += a1 * w0.y; acc[1][2] += a1 * w0.z; acc[1][3] += a1 * w0.w;
      acc[1][4] += a1 * w1.x; acc[1][5] += a1 * w1.y; acc[1][6] += a1 * w1.z; acc[1][7] += a1 * w1.w;
      acc[2][0] += a2 * w0.x; acc[2][1] += a2 * w0.y; acc[2][2] += a2 * w0.z; acc[2][3] += a2 * w0.w;
      acc[2][4] += a2 * w1.x; acc[2][5] += a2 * w1.y; acc[2][6] += a2 * w1.z; acc[2][7] += a2 * w1.w;
      acc[3][0] += a3 * w0.x; acc[3][1] += a3 * w0.y; acc[3][2] += a3 * w0.z; acc[3][3] += a3 * w0.w;
      acc[3][4] += a3 * w1.x; acc[3][5] += a3 * w1.y; acc[3][6] += a3 * w1.z; acc[3][7] += a3 * w1.w;
    }
    __syncthreads();
  }

  if (c0 < 64) {
#pragma unroll
    for (int i = 0; i < 4; ++i) {
      int gr = rowBase + r0 + i;
      if (gr < M) {
        uint4 p;
        p.x = pk_bf16(acc[i][0], acc[i][1]);
        p.y = pk_bf16(acc[i][2], acc[i][3]);
        p.z = pk_bf16(acc[i][4], acc[i][5]);
        p.w = pk_bf16(acc[i][6], acc[i][7]);
        *reinterpret_cast<uint4*>(h + (size_t)gr * 64 + c0) = p;
      }
    }
  } else {
    int cg = c0 - 64;
#pragma unroll
    for (int i = 0; i < 4; ++i) {
      int gr = rowBase + r0 + i;
      if (gr < M) {
        float4 v0, v1;
        v0.x = acc[i][0]; v0.y = acc[i][1]; v0.z = acc[i][2]; v0.w = acc[i][3];
        v1.x = acc[i][4]; v1.y = acc[i][5]; v1.z = acc[i][6]; v1.w = acc[i][7];
        *reinterpret_cast<float4*>(g + (size_t)gr * 64 + cg) = v0;
        *reinterpret_cast<float4*>(g + (size_t)gr * 64 + cg + 4) = v1;
      }
    }
  }
}

// ---------------- launch ----------------

extern "C" void kernel_launch(void* const* d_in, const int* in_sizes, int n_in,
                              void* d_out, int out_size, void* d_ws, size_t ws_size,
                              hipStream_t stream) {
  const float* x_s = (const float*)d_in[0];
  const float* x_t = (const float*)d_in[1];
  const int* s2t = (const int*)d_in[2];
  const int* t2s = (const int*)d_in[3];
  const float* W1s_l = (const float*)d_in[4];
  const float* W1s_r = (const float*)d_in[5];
  const float* b1s = (const float*)d_in[6];
  const float* W1t_l = (const float*)d_in[7];
  const float* W1t_r = (const float*)d_in[8];
  const float* b1t = (const float*)d_in[9];
  const float* W2s_l = (const float*)d_in[10];
  const float* W2s_r = (const float*)d_in[11];
  const float* b2s = (const float*)d_in[12];
  const float* W2t_l = (const float*)d_in[13];
  const float* W2t_r = (const float*)d_in[14];
  const float* b2t = (const float*)d_in[15];

  const int NS = in_sizes[0] / 128;
  const int NT = in_sizes[1] / 128;
  const int E = in_sizes[2] / 2;

  char* ws = (char*)d_ws;
  size_t off = 0;
  auto alloc = [&](size_t bytes) -> void* {
    void* p = ws + off;
    off = (off + bytes + 255) & ~(size_t)255;
    return p;
  };

  int* rowptr_s = (int*)alloc((size_t)(NS + 1) * 4);
  int* rowptr_t = (int*)alloc((size_t)(NT + 1) * 4);
  int* csr_s = (int*)alloc((size_t)E * 4);
  int* csr_t = (int*)alloc((size_t)E * 4);

  // R2: CSR-build temps (bkt, H, tot, basep)  ->  later mean_s|mean_t -> h/g
  char* R2 = (char*)alloc((size_t)(NS + NT) * 128 * 4);
  // R3: xs_bf|xt_bf -> later xnew_s|xnew_t
  char* R3 = (char*)alloc((size_t)(NS + NT) * 128 * 4);

  const int nblk = cdiv(E, EPB);

  // build temps overlaid on R2 (consumed before mean is written)
  int2* bkt = (int2*)R2;                                  // E*8 bytes
  int* H = (int*)(R2 + (size_t)E * 8);                    // nblk*NBKT*4
  int* tot = (int*)(R2 + (size_t)E * 8 + (size_t)nblk * NBKT * 4);
  int* basep = tot + NBKT;                                // NBKT+1 ints

  float* mean_s = (float*)R2;
  float* mean_t = mean_s + (size_t)NS * 128;
  u16* h_s = (u16*)R2;
  u16* h_t = h_s + (size_t)NS * 64;
  float* g_s = (float*)(h_t + (size_t)NT * 64);
  float* g_t = g_s + (size_t)NS * 64;

  u16* xs_bf = (u16*)R3;
  u16* xt_bf = xs_bf + (size_t)NS * 128;
  float* xnew_s = (float*)R3;
  float* xnew_t = xnew_s + (size_t)NS * 128;

  float* z_s = (float*)d_out;
  float* z_t = (float*)d_out + (size_t)NS * 64;

  // fp32 -> bf16 feature copies (independent of CSR build)
  cvt_bf16_k<<<cdiv(NS * 64, 256), 256, 0, stream>>>(x_s, (u32*)xs_bf, NS * 64);
  cvt_bf16_k<<<cdiv(NT * 64, 256), 256, 0, stream>>>(x_t, (u32*)xt_bf, NT * 64);

  // ----- CSR build: dsts in S (edge list t2s: row = t idx, col = s idx) -----
  hist_k<<<nblk, 256, 0, stream>>>(t2s + E, E, H);
  scanH_k<<<NBKT, 64, 0, stream>>>(H, nblk, tot);
  baseScan_k<<<1, NBKT, 0, stream>>>(tot, basep, E);
  scatter_k<<<nblk, 256, 0, stream>>>(t2s, t2s + E, E, H, basep, bkt);
  finalize_k<<<cdiv(NS, BNODES), 256, 0, stream>>>(bkt, basep, NS, E, rowptr_s, csr_s);

  // ----- CSR build: dsts in T (edge list s2t) -----
  hist_k<<<nblk, 256, 0, stream>>>(s2t + E, E, H);
  scanH_k<<<NBKT, 64, 0, stream>>>(H, nblk, tot);
  baseScan_k<<<1, NBKT, 0, stream>>>(tot, basep, E);
  scatter_k<<<nblk, 256, 0, stream>>>(s2t, s2t + E, E, H, basep, bkt);
  finalize_k<<<cdiv(NT, BNODES), 256, 0, stream>>>(bkt, basep, NT, E, rowptr_t, csr_t);

  // ----- layer 1 -----
  agg128_k<<<cdiv(NS, 4), 256, 0, stream>>>(xt_bf, rowptr_s, csr_s, NS, mean_s);
  agg128_k<<<cdiv(NT, 4), 256, 0, stream>>>(xs_bf, rowptr_t, csr_t, NT, mean_t);
  gemm_l1_k<<<cdiv(NS, 64), 256, 0, stream>>>(mean_s, x_s, W1s_l, W1s_r, b1s, xnew_s, NS);
  gemm_l1_k<<<cdiv(NT, 64), 256, 0, stream>>>(mean_t, x_t, W1t_l, W1t_r, b1t, xnew_t, NT);

  // ----- layer 2 (transform-first) -----
  gemm_l2_k<<<cdiv(NS, 64), 256, 0, stream>>>(xnew_s, W2t_l, W2s_r, h_s, g_s, NS);
  gemm_l2_k<<<cdiv(NT, 64), 256, 0, stream>>>(xnew_t, W2s_l, W2t_r, h_t, g_t, NT);

  agg64_epi_k<<<cdiv(NS, 4), 256, 0, stream>>>(h_t, rowptr_s, csr_s, NS, g_s, b2s, z_s);
  agg64_epi_k<<<cdiv(NT, 4), 256, 0, stream>>>(h_s, rowptr_t, csr_t, NT, g_t, b2t, z_t);
}

// Round 4
// 415.442 us; speedup vs baseline: 2.3617x; 1.2438x over previous
//
#include <hip/hip_runtime.h>

typedef unsigned int u32;
typedef unsigned short u16;
typedef __attribute__((ext_vector_type(4))) float f32x4;
typedef __attribute__((ext_vector_type(8))) short bf16x8;

static inline int cdiv(int a, int b) { return (a + b - 1) / b; }

#define NBKT 512   // buckets = dst >> BSHIFT
#define BSHIFT 7   // 128 nodes per bucket
#define BNODES 128
#define EPB 4096   // edges per block for hist/scatter

// ---------- bf16 helpers ----------
__device__ inline u32 pk_bf16(float a, float b) {
  u32 ua = __builtin_bit_cast(u32, a);
  ua += 0x7fffu + ((ua >> 16) & 1u);
  u32 ub = __builtin_bit_cast(u32, b);
  ub += 0x7fffu + ((ub >> 16) & 1u);
  return (ua >> 16) | (ub & 0xffff0000u);
}
__device__ inline float bf_lo(u32 v) { return __builtin_bit_cast(float, v << 16); }
__device__ inline float bf_hi(u32 v) { return __builtin_bit_cast(float, v & 0xffff0000u); }

// ---------- fp32 -> bf16 convert (2 elems/thread) ----------
__global__ __launch_bounds__(256) void cvt_bf16_k(const float* __restrict__ in,
                                                  u32* __restrict__ out, int n2) {
  int i = blockIdx.x * 256 + threadIdx.x;
  if (i < n2) {
    float2 v = *reinterpret_cast<const float2*>(in + (size_t)i * 2);
    out[i] = pk_bf16(v.x, v.y);
  }
}

// ---------- weights -> transposed bf16, packed buffer ----------
// layout (elems): Wt1s_l @0, Wt1s_r @16384, Wt1t_l @32768, Wt1t_r @49152 (each [128][128])
//                 Wt2A_s @65536, Wt2B_s @73728, Wt2A_t @81920, Wt2B_t @90112 (each [64][128])
__global__ __launch_bounds__(256) void cvtW_k(const float* __restrict__ W1sl,
                                              const float* __restrict__ W1sr,
                                              const float* __restrict__ W1tl,
                                              const float* __restrict__ W1tr,
                                              const float* __restrict__ W2A_s,
                                              const float* __restrict__ W2B_s,
                                              const float* __restrict__ W2A_t,
                                              const float* __restrict__ W2B_t,
                                              u16* __restrict__ out) {
  int seg = blockIdx.x * 256 + threadIdx.x;  // 12288 total, 8 bf16 per seg
  if (seg >= 12288) return;
  const float* W;
  int ncol, base, local;
  if (seg < 8192) {
    int m = seg >> 11; local = seg & 2047; ncol = 128; base = m * 16384;
    W = m == 0 ? W1sl : m == 1 ? W1sr : m == 2 ? W1tl : W1tr;
  } else {
    int m = (seg - 8192) >> 10; local = (seg - 8192) & 1023; ncol = 64; base = 65536 + m * 8192;
    W = m == 0 ? W2A_s : m == 1 ? W2B_s : m == 2 ? W2A_t : W2B_t;
  }
  int col = local >> 4;        // 16 segs (of 8 k) per col
  int k0 = (local & 15) * 8;
  u16 tmp[8];
#pragma unroll
  for (int e = 0; e < 8; ++e) {
    float v = W[(size_t)(k0 + e) * ncol + col];
    tmp[e] = (u16)(pk_bf16(v, 0.f) & 0xffffu);
  }
  *reinterpret_cast<uint4*>(out + (size_t)base + col * 128 + k0) =
      *reinterpret_cast<uint4*>(tmp);
}

// ================= CSR build via bucketed counting sort =================

__global__ __launch_bounds__(256) void hist_k(const int* __restrict__ col, int E,
                                              int* __restrict__ H) {
  __shared__ int h[NBKT];
  int t = threadIdx.x;
  for (int i = t; i < NBKT; i += 256) h[i] = 0;
  __syncthreads();
  int base = blockIdx.x * EPB;
  int end = min(base + EPB, E);
  for (int i = base + t; i < end; i += 256) atomicAdd(&h[col[i] >> BSHIFT], 1);
  __syncthreads();
  int* Hrow = H + (size_t)blockIdx.x * NBKT;
  for (int i = t; i < NBKT; i += 256) Hrow[i] = h[i];
}

__global__ __launch_bounds__(64) void scanH_k(int* __restrict__ H, int nblk,
                                              int* __restrict__ tot) {
  int b = blockIdx.x;
  int lane = threadIdx.x;
  int carry = 0;
  for (int c = 0; c < nblk; c += 64) {
    int idx = c + lane;
    int v = (idx < nblk) ? H[(size_t)idx * NBKT + b] : 0;
    int s = v;
#pragma unroll
    for (int off = 1; off < 64; off <<= 1) {
      int x = __shfl_up(s, off);
      if (lane >= off) s += x;
    }
    if (idx < nblk) H[(size_t)idx * NBKT + b] = s - v + carry;
    carry += __shfl(s, 63);
  }
  if (lane == 0) tot[b] = carry;
}

__global__ __launch_bounds__(NBKT) void baseScan_k(const int* __restrict__ tot,
                                                   int* __restrict__ basep, int E) {
  __shared__ int sm[NBKT];
  int t = threadIdx.x;
  int v = tot[t];
  sm[t] = v;
  __syncthreads();
  for (int off = 1; off < NBKT; off <<= 1) {
    int x = (t >= off) ? sm[t - off] : 0;
    __syncthreads();
    if (t >= off) sm[t] += x;
    __syncthreads();
  }
  basep[t] = sm[t] - v;
  if (t == NBKT - 1) basep[NBKT] = E;
}

__global__ __launch_bounds__(256) void scatter_k(const int* __restrict__ row,
                                                 const int* __restrict__ col, int E,
                                                 const int* __restrict__ H,
                                                 const int* __restrict__ basep,
                                                 int2* __restrict__ bkt) {
  __shared__ int cur[NBKT];
  int t = threadIdx.x;
  const int* Hrow = H + (size_t)blockIdx.x * NBKT;
  for (int i = t; i < NBKT; i += 256) cur[i] = basep[i] + Hrow[i];
  __syncthreads();
  int base = blockIdx.x * EPB;
  int end = min(base + EPB, E);
  for (int i = base + t; i < end; i += 256) {
    int c = col[i];
    int p = atomicAdd(&cur[c >> BSHIFT], 1);
    bkt[p] = make_int2(row[i], c);
  }
}

__global__ __launch_bounds__(256) void finalize_k(const int2* __restrict__ bkt,
                                                  const int* __restrict__ basep,
                                                  int N, int Etot,
                                                  int* __restrict__ rowptr,
                                                  int* __restrict__ csr) {
  __shared__ int cnt[BNODES];
  __shared__ int excl[BNODES];
  int b = blockIdx.x;
  int t = threadIdx.x;
  int node0 = b << BSHIFT;
  int rs = basep[b], re = basep[b + 1];
  if (t < BNODES) cnt[t] = 0;
  __syncthreads();
  for (int i = rs + t; i < re; i += 256) {
    int2 p = bkt[i];
    atomicAdd(&cnt[p.y - node0], 1);
  }
  __syncthreads();
  if (t < BNODES) excl[t] = cnt[t];
  __syncthreads();
  for (int off = 1; off < BNODES; off <<= 1) {
    int x = 0;
    if (t < BNODES && t >= off) x = excl[t - off];
    __syncthreads();
    if (t < BNODES && t >= off) excl[t] += x;
    __syncthreads();
  }
  if (t < BNODES) {
    int node = node0 + t;
    int start = rs + excl[t] - cnt[t];
    if (node < N) rowptr[node] = start;
    cnt[t] = start;
  }
  if (b == 0 && t == 0) rowptr[N] = Etot;
  __syncthreads();
  for (int i = rs + t; i < re; i += 256) {
    int2 p = bkt[i];
    int pos = atomicAdd(&cnt[p.y - node0], 1);
    csr[pos] = p.x;
  }
}

// ---------------- mean aggregation, 128-wide bf16 gather -> bf16 mean ----------------

__global__ __launch_bounds__(256) void agg128_k(const u16* __restrict__ xsrc,
                                                const int* __restrict__ rowptr,
                                                const int* __restrict__ csr, int n_dst,
                                                u32* __restrict__ outm) {
  int node = blockIdx.x * 4 + (threadIdx.x >> 6);
  if (node >= n_dst) return;
  int lane = threadIdx.x & 63;
  int s = rowptr[node], e = rowptr[node + 1];
  float ax = 0.f, ay = 0.f;
  int i = s;
  for (; i + 4 <= e; i += 4) {
    int i0 = csr[i], i1 = csr[i + 1], i2 = csr[i + 2], i3 = csr[i + 3];
    u32 v0 = *reinterpret_cast<const u32*>(xsrc + (size_t)i0 * 128 + lane * 2);
    u32 v1 = *reinterpret_cast<const u32*>(xsrc + (size_t)i1 * 128 + lane * 2);
    u32 v2 = *reinterpret_cast<const u32*>(xsrc + (size_t)i2 * 128 + lane * 2);
    u32 v3 = *reinterpret_cast<const u32*>(xsrc + (size_t)i3 * 128 + lane * 2);
    ax += (bf_lo(v0) + bf_lo(v1)) + (bf_lo(v2) + bf_lo(v3));
    ay += (bf_hi(v0) + bf_hi(v1)) + (bf_hi(v2) + bf_hi(v3));
  }
  for (; i < e; ++i) {
    u32 v0 = *reinterpret_cast<const u32*>(xsrc + (size_t)csr[i] * 128 + lane * 2);
    ax += bf_lo(v0);
    ay += bf_hi(v0);
  }
  float inv = (e > s) ? 1.f / (float)(e - s) : 0.f;
  outm[(size_t)node * 64 + lane] = pk_bf16(ax * inv, ay * inv);
}

// ---------------- mean aggregation, 64-wide bf16 gather + epilogue ----------------

__global__ __launch_bounds__(256) void agg64_epi_k(const u16* __restrict__ h,
                                                   const int* __restrict__ rowptr,
                                                   const int* __restrict__ csr, int n_dst,
                                                   const float* __restrict__ g,
                                                   const float* __restrict__ bias,
                                                   float* __restrict__ z) {
  int node = blockIdx.x * 4 + (threadIdx.x >> 6);
  if (node >= n_dst) return;
  int lane = threadIdx.x & 63;
  int half = lane >> 5;
  int fl = lane & 31;
  int s = rowptr[node], e = rowptr[node + 1];
  float ax = 0.f, ay = 0.f;
  int i = s + half;
  for (; i + 2 < e; i += 4) {
    int i0 = csr[i], i1 = csr[i + 2];
    u32 v0 = *reinterpret_cast<const u32*>(h + (size_t)i0 * 64 + fl * 2);
    u32 v1 = *reinterpret_cast<const u32*>(h + (size_t)i1 * 64 + fl * 2);
    ax += bf_lo(v0) + bf_lo(v1);
    ay += bf_hi(v0) + bf_hi(v1);
  }
  for (; i < e; i += 2) {
    u32 v0 = *reinterpret_cast<const u32*>(h + (size_t)csr[i] * 64 + fl * 2);
    ax += bf_lo(v0);
    ay += bf_hi(v0);
  }
  ax += __shfl_xor(ax, 32);
  ay += __shfl_xor(ay, 32);
  if (lane < 32) {
    float inv = (e > s) ? 1.f / (float)(e - s) : 0.f;
    float2 gv = *reinterpret_cast<const float2*>(g + (size_t)node * 64 + fl * 2);
    float2 bv = *reinterpret_cast<const float2*>(bias + fl * 2);
    float2 r;
    r.x = ax * inv + gv.x + bv.x;
    r.y = ay * inv + gv.y + bv.y;
    *reinterpret_cast<float2*>(z + (size_t)node * 64 + fl * 2) = r;
  }
}

// ---------------- layer-1 MFMA GEMM: out_bf16 = [A0|A1] @ [W0;W1] + bias ----------------
// A0,A1: [M][128] bf16 row-major. Wt0,Wt1: [128 cols][128 k] bf16 (transposed).
// Swapped operands: mfma(w_frag, x_frag) -> lane holds 4 consecutive COLS of one row.
// 32 rows/wave, 128 rows/block.

__global__ __launch_bounds__(256) void gemm1_mfma_k(const u16* __restrict__ A0,
                                                    const u16* __restrict__ A1,
                                                    const u16* __restrict__ Wt0,
                                                    const u16* __restrict__ Wt1,
                                                    const float* __restrict__ bias,
                                                    u16* __restrict__ out, int M) {
  const int lane = threadIdx.x & 63;
  const int wid = threadIdx.x >> 6;
  const int r16 = lane & 15;
  const int kg = lane >> 4;  // 0..3
  const int rowBase = blockIdx.x * 128 + wid * 32;

  f32x4 acc[2][8];
#pragma unroll
  for (int i = 0; i < 2; ++i)
#pragma unroll
    for (int j = 0; j < 8; ++j) acc[i][j] = (f32x4){0.f, 0.f, 0.f, 0.f};

  const int r0 = min(rowBase + r16, M - 1);
  const int r1 = min(rowBase + 16 + r16, M - 1);

#pragma unroll
  for (int ch = 0; ch < 8; ++ch) {
    const u16* A = (ch < 4) ? A0 : A1;
    const u16* Wt = (ch < 4) ? Wt0 : Wt1;
    const int koff = (ch & 3) * 32 + kg * 8;
    bf16x8 x0 = *reinterpret_cast<const bf16x8*>(A + (size_t)r0 * 128 + koff);
    bf16x8 x1 = *reinterpret_cast<const bf16x8*>(A + (size_t)r1 * 128 + koff);
#pragma unroll
    for (int cb = 0; cb < 8; ++cb) {
      bf16x8 w = *reinterpret_cast<const bf16x8*>(Wt + (size_t)(cb * 16 + r16) * 128 + koff);
      acc[0][cb] = __builtin_amdgcn_mfma_f32_16x16x32_bf16(w, x0, acc[0][cb], 0, 0, 0);
      acc[1][cb] = __builtin_amdgcn_mfma_f32_16x16x32_bf16(w, x1, acc[1][cb], 0, 0, 0);
    }
  }

#pragma unroll
  for (int cb = 0; cb < 8; ++cb) {
    float4 bv = *reinterpret_cast<const float4*>(bias + cb * 16 + kg * 4);
#pragma unroll
    for (int rb = 0; rb < 2; ++rb) {
      int row = rowBase + rb * 16 + r16;
      if (row < M) {
        f32x4 a = acc[rb][cb];
        uint2 p;
        p.x = pk_bf16(a[0] + bv.x, a[1] + bv.y);
        p.y = pk_bf16(a[2] + bv.z, a[3] + bv.w);
        *reinterpret_cast<uint2*>(out + (size_t)row * 128 + cb * 16 + kg * 4) = p;
      }
    }
  }
}

// ---------------- layer-2 MFMA GEMM: h_bf16 = X@Wa, g_f32 = X@Wb ----------------
// X: [M][128] bf16. WtA,WtB: [64 cols][128 k] bf16 (transposed). 32 rows/wave.

__global__ __launch_bounds__(256) void gemm2_mfma_k(const u16* __restrict__ X,
                                                    const u16* __restrict__ WtA,
                                                    const u16* __restrict__ WtB,
                                                    u16* __restrict__ h,
                                                    float* __restrict__ g, int M) {
  const int lane = threadIdx.x & 63;
  const int wid = threadIdx.x >> 6;
  const int r16 = lane & 15;
  const int kg = lane >> 4;
  const int rowBase = blockIdx.x * 128 + wid * 32;

  f32x4 acc[2][8];
#pragma unroll
  for (int i = 0; i < 2; ++i)
#pragma unroll
    for (int j = 0; j < 8; ++j) acc[i][j] = (f32x4){0.f, 0.f, 0.f, 0.f};

  const int r0 = min(rowBase + r16, M - 1);
  const int r1 = min(rowBase + 16 + r16, M - 1);

#pragma unroll
  for (int ch = 0; ch < 4; ++ch) {
    const int koff = ch * 32 + kg * 8;
    bf16x8 x0 = *reinterpret_cast<const bf16x8*>(X + (size_t)r0 * 128 + koff);
    bf16x8 x1 = *reinterpret_cast<const bf16x8*>(X + (size_t)r1 * 128 + koff);
#pragma unroll
    for (int cb = 0; cb < 8; ++cb) {
      const u16* Wt = (cb < 4) ? WtA : WtB;
      bf16x8 w = *reinterpret_cast<const bf16x8*>(Wt + (size_t)((cb & 3) * 16 + r16) * 128 + koff);
      acc[0][cb] = __builtin_amdgcn_mfma_f32_16x16x32_bf16(w, x0, acc[0][cb], 0, 0, 0);
      acc[1][cb] = __builtin_amdgcn_mfma_f32_16x16x32_bf16(w, x1, acc[1][cb], 0, 0, 0);
    }
  }

#pragma unroll
  for (int cb = 0; cb < 8; ++cb) {
#pragma unroll
    for (int rb = 0; rb < 2; ++rb) {
      int row = rowBase + rb * 16 + r16;
      if (row < M) {
        f32x4 a = acc[rb][cb];
        if (cb < 4) {
          uint2 p;
          p.x = pk_bf16(a[0], a[1]);
          p.y = pk_bf16(a[2], a[3]);
          *reinterpret_cast<uint2*>(h + (size_t)row * 64 + cb * 16 + kg * 4) = p;
        } else {
          *reinterpret_cast<f32x4*>(g + (size_t)row * 64 + (cb - 4) * 16 + kg * 4) = a;
        }
      }
    }
  }
}

// ---------------- launch ----------------

extern "C" void kernel_launch(void* const* d_in, const int* in_sizes, int n_in,
                              void* d_out, int out_size, void* d_ws, size_t ws_size,
                              hipStream_t stream) {
  const float* x_s = (const float*)d_in[0];
  const float* x_t = (const float*)d_in[1];
  const int* s2t = (const int*)d_in[2];
  const int* t2s = (const int*)d_in[3];
  const float* W1s_l = (const float*)d_in[4];
  const float* W1s_r = (const float*)d_in[5];
  const float* b1s = (const float*)d_in[6];
  const float* W1t_l = (const float*)d_in[7];
  const float* W1t_r = (const float*)d_in[8];
  const float* b1t = (const float*)d_in[9];
  const float* W2s_l = (const float*)d_in[10];
  const float* W2s_r = (const float*)d_in[11];
  const float* b2s = (const float*)d_in[12];
  const float* W2t_l = (const float*)d_in[13];
  const float* W2t_r = (const float*)d_in[14];
  const float* b2t = (const float*)d_in[15];

  const int NS = in_sizes[0] / 128;
  const int NT = in_sizes[1] / 128;
  const int E = in_sizes[2] / 2;

  char* ws = (char*)d_ws;
  size_t off = 0;
  auto alloc = [&](size_t bytes) -> void* {
    void* p = ws + off;
    off = (off + bytes + 255) & ~(size_t)255;
    return p;
  };

  int* rowptr_s = (int*)alloc((size_t)(NS + 1) * 4);
  int* rowptr_t = (int*)alloc((size_t)(NT + 1) * 4);
  int* csr_s = (int*)alloc((size_t)E * 4);
  int* csr_t = (int*)alloc((size_t)E * 4);
  u16* Wt = (u16*)alloc(98304 * 2);  // packed transposed bf16 weights

  // R2: CSR-build temps (bkt, H, tot, basep) -> later mean_bf -> h/g
  char* R2 = (char*)alloc((size_t)(NS + NT) * 128 * 4);
  // R3: xs_bf|xt_bf|xnew_s|xnew_t (all bf16)
  char* R3 = (char*)alloc((size_t)(NS + NT) * 128 * 4);

  const int nblk = cdiv(E, EPB);

  int2* bkt = (int2*)R2;
  int* H = (int*)(R2 + (size_t)E * 8);
  int* tot = (int*)(R2 + (size_t)E * 8 + (size_t)nblk * NBKT * 4);
  int* basep = tot + NBKT;

  u16* mean_s = (u16*)R2;                    // [NS][128] bf16
  u16* mean_t = mean_s + (size_t)NS * 128;
  u16* h_s = (u16*)R2;
  u16* h_t = h_s + (size_t)NS * 64;
  float* g_s = (float*)(h_t + (size_t)NT * 64);
  float* g_t = g_s + (size_t)NS * 64;

  u16* xs_bf = (u16*)R3;
  u16* xt_bf = xs_bf + (size_t)NS * 128;
  u16* xnew_s = xt_bf + (size_t)NT * 128;    // bf16 now
  u16* xnew_t = xnew_s + (size_t)NS * 128;

  // Wt sub-pointers (elems)
  u16* Wt1s_l = Wt;
  u16* Wt1s_r = Wt + 16384;
  u16* Wt1t_l = Wt + 32768;
  u16* Wt1t_r = Wt + 49152;
  u16* Wt2A_s = Wt + 65536;  // W2t_l^T (h_s)
  u16* Wt2B_s = Wt + 73728;  // W2s_r^T (g_s)
  u16* Wt2A_t = Wt + 81920;  // W2s_l^T (h_t)
  u16* Wt2B_t = Wt + 90112;  // W2t_r^T (g_t)

  float* z_s = (float*)d_out;
  float* z_t = (float*)d_out + (size_t)NS * 64;

  // conversions (independent of CSR build)
  cvt_bf16_k<<<cdiv(NS * 64, 256), 256, 0, stream>>>(x_s, (u32*)xs_bf, NS * 64);
  cvt_bf16_k<<<cdiv(NT * 64, 256), 256, 0, stream>>>(x_t, (u32*)xt_bf, NT * 64);
  cvtW_k<<<48, 256, 0, stream>>>(W1s_l, W1s_r, W1t_l, W1t_r,
                                 W2t_l, W2s_r, W2s_l, W2t_r, Wt);

  // ----- CSR build: dsts in S (edge list t2s) -----
  hist_k<<<nblk, 256, 0, stream>>>(t2s + E, E, H);
  scanH_k<<<NBKT, 64, 0, stream>>>(H, nblk, tot);
  baseScan_k<<<1, NBKT, 0, stream>>>(tot, basep, E);
  scatter_k<<<nblk, 256, 0, stream>>>(t2s, t2s + E, E, H, basep, bkt);
  finalize_k<<<cdiv(NS, BNODES), 256, 0, stream>>>(bkt, basep, NS, E, rowptr_s, csr_s);

  // ----- CSR build: dsts in T (edge list s2t) -----
  hist_k<<<nblk, 256, 0, stream>>>(s2t + E, E, H);
  scanH_k<<<NBKT, 64, 0, stream>>>(H, nblk, tot);
  baseScan_k<<<1, NBKT, 0, stream>>>(tot, basep, E);
  scatter_k<<<nblk, 256, 0, stream>>>(s2t, s2t + E, E, H, basep, bkt);
  finalize_k<<<cdiv(NT, BNODES), 256, 0, stream>>>(bkt, basep, NT, E, rowptr_t, csr_t);

  // ----- layer 1 -----
  agg128_k<<<cdiv(NS, 4), 256, 0, stream>>>(xt_bf, rowptr_s, csr_s, NS, (u32*)mean_s);
  agg128_k<<<cdiv(NT, 4), 256, 0, stream>>>(xs_bf, rowptr_t, csr_t, NT, (u32*)mean_t);
  gemm1_mfma_k<<<cdiv(NS, 128), 256, 0, stream>>>(mean_s, xs_bf, Wt1s_l, Wt1s_r, b1s, xnew_s, NS);
  gemm1_mfma_k<<<cdiv(NT, 128), 256, 0, stream>>>(mean_t, xt_bf, Wt1t_l, Wt1t_r, b1t, xnew_t, NT);

  // ----- layer 2 (transform-first) -----
  gemm2_mfma_k<<<cdiv(NS, 128), 256, 0, stream>>>(xnew_s, Wt2A_s, Wt2B_s, h_s, g_s, NS);
  gemm2_mfma_k<<<cdiv(NT, 128), 256, 0, stream>>>(xnew_t, Wt2A_t, Wt2B_t, h_t, g_t, NT);

  agg64_epi_k<<<cdiv(NS, 4), 256, 0, stream>>>(h_t, rowptr_s, csr_s, NS, g_s, b2s, z_s);
  agg64_epi_k<<<cdiv(NT, 4), 256, 0, stream>>>(h_s, rowptr_t, csr_t, NT, g_t, b2t, z_t);
}

// Round 5
// 410.515 us; speedup vs baseline: 2.3900x; 1.0120x over previous
//
#include <hip/hip_runtime.h>

typedef unsigned int u32;
typedef unsigned short u16;
typedef unsigned char u8;
typedef __attribute__((ext_vector_type(4))) float f32x4;
typedef __attribute__((ext_vector_type(2))) float f32x2;
typedef __attribute__((ext_vector_type(8))) short bf16x8;

static inline int cdiv(int a, int b) { return (a + b - 1) / b; }

#define NBKT 512   // buckets = dst >> BSHIFT
#define BSHIFT 7   // 128 nodes per bucket
#define BNODES 128
#define EPB 4096   // edges per block for hist/scatter

// ---------- bf16 helpers ----------
__device__ inline u32 pk_bf16(float a, float b) {
  u32 ua = __builtin_bit_cast(u32, a);
  ua += 0x7fffu + ((ua >> 16) & 1u);
  u32 ub = __builtin_bit_cast(u32, b);
  ub += 0x7fffu + ((ub >> 16) & 1u);
  return (ua >> 16) | (ub & 0xffff0000u);
}
__device__ inline float bf_lo(u32 v) { return __builtin_bit_cast(float, v << 16); }
__device__ inline float bf_hi(u32 v) { return __builtin_bit_cast(float, v & 0xffff0000u); }

// ---------- fp32 -> bf16 convert (2 elems/thread) ----------
__global__ __launch_bounds__(256) void cvt_bf16_k(const float* __restrict__ in,
                                                  u32* __restrict__ out, int n2) {
  int i = blockIdx.x * 256 + threadIdx.x;
  if (i < n2) {
    float2 v = *reinterpret_cast<const float2*>(in + (size_t)i * 2);
    out[i] = pk_bf16(v.x, v.y);
  }
}

// ---------- fp32 -> fp8 e4m3 convert (4 elems/thread) ----------
__global__ __launch_bounds__(256) void cvt_f8_k(const float* __restrict__ in,
                                                u32* __restrict__ out, int n4) {
  int i = blockIdx.x * 256 + threadIdx.x;
  if (i < n4) {
    float4 v = *reinterpret_cast<const float4*>(in + (size_t)i * 4);
    u32 p = 0;
    p = __builtin_amdgcn_cvt_pk_fp8_f32(v.x, v.y, p, false);
    p = __builtin_amdgcn_cvt_pk_fp8_f32(v.z, v.w, p, true);
    out[i] = p;
  }
}

// ---------- weights -> transposed bf16, packed buffer ----------
__global__ __launch_bounds__(256) void cvtW_k(const float* __restrict__ W1sl,
                                              const float* __restrict__ W1sr,
                                              const float* __restrict__ W1tl,
                                              const float* __restrict__ W1tr,
                                              const float* __restrict__ W2A_s,
                                              const float* __restrict__ W2B_s,
                                              const float* __restrict__ W2A_t,
                                              const float* __restrict__ W2B_t,
                                              u16* __restrict__ out) {
  int seg = blockIdx.x * 256 + threadIdx.x;  // 12288 total, 8 bf16 per seg
  if (seg >= 12288) return;
  const float* W;
  int ncol, base, local;
  if (seg < 8192) {
    int m = seg >> 11; local = seg & 2047; ncol = 128; base = m * 16384;
    W = m == 0 ? W1sl : m == 1 ? W1sr : m == 2 ? W1tl : W1tr;
  } else {
    int m = (seg - 8192) >> 10; local = (seg - 8192) & 1023; ncol = 64; base = 65536 + m * 8192;
    W = m == 0 ? W2A_s : m == 1 ? W2B_s : m == 2 ? W2A_t : W2B_t;
  }
  int col = local >> 4;
  int k0 = (local & 15) * 8;
  u16 tmp[8];
#pragma unroll
  for (int e = 0; e < 8; ++e) {
    float v = W[(size_t)(k0 + e) * ncol + col];
    tmp[e] = (u16)(pk_bf16(v, 0.f) & 0xffffu);
  }
  *reinterpret_cast<uint4*>(out + (size_t)base + col * 128 + k0) =
      *reinterpret_cast<uint4*>(tmp);
}

// ================= CSR build via bucketed counting sort =================

__global__ __launch_bounds__(256) void hist_k(const int* __restrict__ col, int E,
                                              int* __restrict__ H) {
  __shared__ int h[NBKT];
  int t = threadIdx.x;
  for (int i = t; i < NBKT; i += 256) h[i] = 0;
  __syncthreads();
  int base = blockIdx.x * EPB;
  int end = min(base + EPB, E);
  for (int i = base + t; i < end; i += 256) atomicAdd(&h[col[i] >> BSHIFT], 1);
  __syncthreads();
  int* Hrow = H + (size_t)blockIdx.x * NBKT;
  for (int i = t; i < NBKT; i += 256) Hrow[i] = h[i];
}

__global__ __launch_bounds__(64) void scanH_k(int* __restrict__ H, int nblk,
                                              int* __restrict__ tot) {
  int b = blockIdx.x;
  int lane = threadIdx.x;
  int carry = 0;
  for (int c = 0; c < nblk; c += 64) {
    int idx = c + lane;
    int v = (idx < nblk) ? H[(size_t)idx * NBKT + b] : 0;
    int s = v;
#pragma unroll
    for (int off = 1; off < 64; off <<= 1) {
      int x = __shfl_up(s, off);
      if (lane >= off) s += x;
    }
    if (idx < nblk) H[(size_t)idx * NBKT + b] = s - v + carry;
    carry += __shfl(s, 63);
  }
  if (lane == 0) tot[b] = carry;
}

__global__ __launch_bounds__(NBKT) void baseScan_k(const int* __restrict__ tot,
                                                   int* __restrict__ basep, int E) {
  __shared__ int sm[NBKT];
  int t = threadIdx.x;
  int v = tot[t];
  sm[t] = v;
  __syncthreads();
  for (int off = 1; off < NBKT; off <<= 1) {
    int x = (t >= off) ? sm[t - off] : 0;
    __syncthreads();
    if (t >= off) sm[t] += x;
    __syncthreads();
  }
  basep[t] = sm[t] - v;
  if (t == NBKT - 1) basep[NBKT] = E;
}

// scatter packed (src<<7 | dst&127) into bucket-contiguous staging
__global__ __launch_bounds__(256) void scatter_k(const int* __restrict__ row,
                                                 const int* __restrict__ col, int E,
                                                 const int* __restrict__ H,
                                                 const int* __restrict__ basep,
                                                 u32* __restrict__ bkt) {
  __shared__ int cur[NBKT];
  int t = threadIdx.x;
  const int* Hrow = H + (size_t)blockIdx.x * NBKT;
  for (int i = t; i < NBKT; i += 256) cur[i] = basep[i] + Hrow[i];
  __syncthreads();
  int base = blockIdx.x * EPB;
  int end = min(base + EPB, E);
  for (int i = base + t; i < end; i += 256) {
    int c = col[i];
    int p = atomicAdd(&cur[c >> BSHIFT], 1);
    bkt[p] = ((u32)row[i] << BSHIFT) | (u32)(c & (BNODES - 1));
  }
}

__global__ __launch_bounds__(256) void finalize_k(const u32* __restrict__ bkt,
                                                  const int* __restrict__ basep,
                                                  int N, int Etot,
                                                  int* __restrict__ rowptr,
                                                  int* __restrict__ csr) {
  __shared__ int cnt[BNODES];
  __shared__ int excl[BNODES];
  int b = blockIdx.x;
  int t = threadIdx.x;
  int node0 = b << BSHIFT;
  int rs = basep[b], re = basep[b + 1];
  if (t < BNODES) cnt[t] = 0;
  __syncthreads();
  for (int i = rs + t; i < re; i += 256) {
    atomicAdd(&cnt[bkt[i] & (BNODES - 1)], 1);
  }
  __syncthreads();
  if (t < BNODES) excl[t] = cnt[t];
  __syncthreads();
  for (int off = 1; off < BNODES; off <<= 1) {
    int x = 0;
    if (t < BNODES && t >= off) x = excl[t - off];
    __syncthreads();
    if (t < BNODES && t >= off) excl[t] += x;
    __syncthreads();
  }
  if (t < BNODES) {
    int node = node0 + t;
    int start = rs + excl[t] - cnt[t];
    if (node < N) rowptr[node] = start;
    cnt[t] = start;
  }
  if (b == 0 && t == 0) rowptr[N] = Etot;
  __syncthreads();
  for (int i = rs + t; i < re; i += 256) {
    u32 p = bkt[i];
    int pos = atomicAdd(&cnt[p & (BNODES - 1)], 1);
    csr[pos] = (int)(p >> BSHIFT);
  }
}

// ---------------- mean aggregation, 128-wide fp8 gather -> bf16 mean ----------------
// row = 128 fp8 = 128B = 32 lanes x u32; 2 edges per wave (lane>>5).

__global__ __launch_bounds__(256) void agg128_f8_k(const u32* __restrict__ xf8,
                                                   const int* __restrict__ rowptr,
                                                   const int* __restrict__ csr, int n_dst,
                                                   u32* __restrict__ outm) {
  int node = blockIdx.x * 4 + (threadIdx.x >> 6);
  if (node >= n_dst) return;
  int lane = threadIdx.x & 63;
  int eh = lane >> 5;   // which edge of the pair
  int fl = lane & 31;   // feature chunk (4 fp8)
  int s = rowptr[node], e = rowptr[node + 1];
  float a0 = 0.f, a1 = 0.f, a2 = 0.f, a3 = 0.f;
  int i = s + eh;
  for (; i + 2 < e; i += 4) {
    u32 v0 = xf8[(size_t)csr[i] * 32 + fl];
    u32 v1 = xf8[(size_t)csr[i + 2] * 32 + fl];
    f32x2 l0 = __builtin_amdgcn_cvt_pk_f32_fp8(v0, false);
    f32x2 h0 = __builtin_amdgcn_cvt_pk_f32_fp8(v0, true);
    f32x2 l1 = __builtin_amdgcn_cvt_pk_f32_fp8(v1, false);
    f32x2 h1 = __builtin_amdgcn_cvt_pk_f32_fp8(v1, true);
    a0 += l0[0] + l1[0];
    a1 += l0[1] + l1[1];
    a2 += h0[0] + h1[0];
    a3 += h0[1] + h1[1];
  }
  for (; i < e; i += 2) {
    u32 v0 = xf8[(size_t)csr[i] * 32 + fl];
    f32x2 l0 = __builtin_amdgcn_cvt_pk_f32_fp8(v0, false);
    f32x2 h0 = __builtin_amdgcn_cvt_pk_f32_fp8(v0, true);
    a0 += l0[0];
    a1 += l0[1];
    a2 += h0[0];
    a3 += h0[1];
  }
  a0 += __shfl_xor(a0, 32);
  a1 += __shfl_xor(a1, 32);
  a2 += __shfl_xor(a2, 32);
  a3 += __shfl_xor(a3, 32);
  if (lane < 32) {
    float inv = (e > s) ? 1.f / (float)(e - s) : 0.f;
    uint2 p;
    p.x = pk_bf16(a0 * inv, a1 * inv);
    p.y = pk_bf16(a2 * inv, a3 * inv);
    *reinterpret_cast<uint2*>(outm + (size_t)node * 64 + fl * 2) = p;
  }
}

// ---------------- mean aggregation, 64-wide bf16 gather + epilogue ----------------

__global__ __launch_bounds__(256) void agg64_epi_k(const u16* __restrict__ h,
                                                   const int* __restrict__ rowptr,
                                                   const int* __restrict__ csr, int n_dst,
                                                   const float* __restrict__ g,
                                                   const float* __restrict__ bias,
                                                   float* __restrict__ z) {
  int node = blockIdx.x * 4 + (threadIdx.x >> 6);
  if (node >= n_dst) return;
  int lane = threadIdx.x & 63;
  int half = lane >> 5;
  int fl = lane & 31;
  int s = rowptr[node], e = rowptr[node + 1];
  float ax = 0.f, ay = 0.f;
  int i = s + half;
  for (; i + 2 < e; i += 4) {
    int i0 = csr[i], i1 = csr[i + 2];
    u32 v0 = *reinterpret_cast<const u32*>(h + (size_t)i0 * 64 + fl * 2);
    u32 v1 = *reinterpret_cast<const u32*>(h + (size_t)i1 * 64 + fl * 2);
    ax += bf_lo(v0) + bf_lo(v1);
    ay += bf_hi(v0) + bf_hi(v1);
  }
  for (; i < e; i += 2) {
    u32 v0 = *reinterpret_cast<const u32*>(h + (size_t)csr[i] * 64 + fl * 2);
    ax += bf_lo(v0);
    ay += bf_hi(v0);
  }
  ax += __shfl_xor(ax, 32);
  ay += __shfl_xor(ay, 32);
  if (lane < 32) {
    float inv = (e > s) ? 1.f / (float)(e - s) : 0.f;
    float2 gv = *reinterpret_cast<const float2*>(g + (size_t)node * 64 + fl * 2);
    float2 bv = *reinterpret_cast<const float2*>(bias + fl * 2);
    float2 r;
    r.x = ax * inv + gv.x + bv.x;
    r.y = ay * inv + gv.y + bv.y;
    *reinterpret_cast<float2*>(z + (size_t)node * 64 + fl * 2) = r;
  }
}

// ---------------- layer-1 MFMA GEMM: out_bf16 = [A0|A1] @ [W0;W1] + bias ----------------

__global__ __launch_bounds__(256) void gemm1_mfma_k(const u16* __restrict__ A0,
                                                    const u16* __restrict__ A1,
                                                    const u16* __restrict__ Wt0,
                                                    const u16* __restrict__ Wt1,
                                                    const float* __restrict__ bias,
                                                    u16* __restrict__ out, int M) {
  const int lane = threadIdx.x & 63;
  const int wid = threadIdx.x >> 6;
  const int r16 = lane & 15;
  const int kg = lane >> 4;
  const int rowBase = blockIdx.x * 128 + wid * 32;

  f32x4 acc[2][8];
#pragma unroll
  for (int i = 0; i < 2; ++i)
#pragma unroll
    for (int j = 0; j < 8; ++j) acc[i][j] = (f32x4){0.f, 0.f, 0.f, 0.f};

  const int r0 = min(rowBase + r16, M - 1);
  const int r1 = min(rowBase + 16 + r16, M - 1);

#pragma unroll
  for (int ch = 0; ch < 8; ++ch) {
    const u16* A = (ch < 4) ? A0 : A1;
    const u16* Wt = (ch < 4) ? Wt0 : Wt1;
    const int koff = (ch & 3) * 32 + kg * 8;
    bf16x8 x0 = *reinterpret_cast<const bf16x8*>(A + (size_t)r0 * 128 + koff);
    bf16x8 x1 = *reinterpret_cast<const bf16x8*>(A + (size_t)r1 * 128 + koff);
#pragma unroll
    for (int cb = 0; cb < 8; ++cb) {
      bf16x8 w = *reinterpret_cast<const bf16x8*>(Wt + (size_t)(cb * 16 + r16) * 128 + koff);
      acc[0][cb] = __builtin_amdgcn_mfma_f32_16x16x32_bf16(w, x0, acc[0][cb], 0, 0, 0);
      acc[1][cb] = __builtin_amdgcn_mfma_f32_16x16x32_bf16(w, x1, acc[1][cb], 0, 0, 0);
    }
  }

#pragma unroll
  for (int cb = 0; cb < 8; ++cb) {
    float4 bv = *reinterpret_cast<const float4*>(bias + cb * 16 + kg * 4);
#pragma unroll
    for (int rb = 0; rb < 2; ++rb) {
      int row = rowBase + rb * 16 + r16;
      if (row < M) {
        f32x4 a = acc[rb][cb];
        uint2 p;
        p.x = pk_bf16(a[0] + bv.x, a[1] + bv.y);
        p.y = pk_bf16(a[2] + bv.z, a[3] + bv.w);
        *reinterpret_cast<uint2*>(out + (size_t)row * 128 + cb * 16 + kg * 4) = p;
      }
    }
  }
}

// ---------------- layer-2 MFMA GEMM: h_bf16 = X@Wa, g_f32 = X@Wb ----------------

__global__ __launch_bounds__(256) void gemm2_mfma_k(const u16* __restrict__ X,
                                                    const u16* __restrict__ WtA,
                                                    const u16* __restrict__ WtB,
                                                    u16* __restrict__ h,
                                                    float* __restrict__ g, int M) {
  const int lane = threadIdx.x & 63;
  const int wid = threadIdx.x >> 6;
  const int r16 = lane & 15;
  const int kg = lane >> 4;
  const int rowBase = blockIdx.x * 128 + wid * 32;

  f32x4 acc[2][8];
#pragma unroll
  for (int i = 0; i < 2; ++i)
#pragma unroll
    for (int j = 0; j < 8; ++j) acc[i][j] = (f32x4){0.f, 0.f, 0.f, 0.f};

  const int r0 = min(rowBase + r16, M - 1);
  const int r1 = min(rowBase + 16 + r16, M - 1);

#pragma unroll
  for (int ch = 0; ch < 4; ++ch) {
    const int koff = ch * 32 + kg * 8;
    bf16x8 x0 = *reinterpret_cast<const bf16x8*>(X + (size_t)r0 * 128 + koff);
    bf16x8 x1 = *reinterpret_cast<const bf16x8*>(X + (size_t)r1 * 128 + koff);
#pragma unroll
    for (int cb = 0; cb < 8; ++cb) {
      const u16* Wt = (cb < 4) ? WtA : WtB;
      bf16x8 w = *reinterpret_cast<const bf16x8*>(Wt + (size_t)((cb & 3) * 16 + r16) * 128 + koff);
      acc[0][cb] = __builtin_amdgcn_mfma_f32_16x16x32_bf16(w, x0, acc[0][cb], 0, 0, 0);
      acc[1][cb] = __builtin_amdgcn_mfma_f32_16x16x32_bf16(w, x1, acc[1][cb], 0, 0, 0);
    }
  }

#pragma unroll
  for (int cb = 0; cb < 8; ++cb) {
#pragma unroll
    for (int rb = 0; rb < 2; ++rb) {
      int row = rowBase + rb * 16 + r16;
      if (row < M) {
        f32x4 a = acc[rb][cb];
        if (cb < 4) {
          uint2 p;
          p.x = pk_bf16(a[0], a[1]);
          p.y = pk_bf16(a[2], a[3]);
          *reinterpret_cast<uint2*>(h + (size_t)row * 64 + cb * 16 + kg * 4) = p;
        } else {
          *reinterpret_cast<f32x4*>(g + (size_t)row * 64 + (cb - 4) * 16 + kg * 4) = a;
        }
      }
    }
  }
}

// ---------------- launch ----------------

extern "C" void kernel_launch(void* const* d_in, const int* in_sizes, int n_in,
                              void* d_out, int out_size, void* d_ws, size_t ws_size,
                              hipStream_t stream) {
  const float* x_s = (const float*)d_in[0];
  const float* x_t = (const float*)d_in[1];
  const int* s2t = (const int*)d_in[2];
  const int* t2s = (const int*)d_in[3];
  const float* W1s_l = (const float*)d_in[4];
  const float* W1s_r = (const float*)d_in[5];
  const float* b1s = (const float*)d_in[6];
  const float* W1t_l = (const float*)d_in[7];
  const float* W1t_r = (const float*)d_in[8];
  const float* b1t = (const float*)d_in[9];
  const float* W2s_l = (const float*)d_in[10];
  const float* W2s_r = (const float*)d_in[11];
  const float* b2s = (const float*)d_in[12];
  const float* W2t_l = (const float*)d_in[13];
  const float* W2t_r = (const float*)d_in[14];
  const float* b2t = (const float*)d_in[15];

  const int NS = in_sizes[0] / 128;
  const int NT = in_sizes[1] / 128;
  const int E = in_sizes[2] / 2;

  char* ws = (char*)d_ws;
  size_t off = 0;
  auto alloc = [&](size_t bytes) -> void* {
    void* p = ws + off;
    off = (off + bytes + 255) & ~(size_t)255;
    return p;
  };

  int* rowptr_s = (int*)alloc((size_t)(NS + 1) * 4);
  int* rowptr_t = (int*)alloc((size_t)(NT + 1) * 4);
  int* csr_s = (int*)alloc((size_t)E * 4);
  int* csr_t = (int*)alloc((size_t)E * 4);
  u16* Wt = (u16*)alloc(98304 * 2);

  // R2 ((NS+NT)*512 B): head = CSR temps -> mean_bf -> h/g; tail = fp8 x copies
  char* R2 = (char*)alloc((size_t)(NS + NT) * 512);
  // R3: xs_bf|xt_bf|xnew_s|xnew_t (all bf16)
  char* R3 = (char*)alloc((size_t)(NS + NT) * 512);

  const int nblk = cdiv(E, EPB);

  u32* bkt = (u32*)R2;                                    // E*4 bytes
  int* H = (int*)(R2 + (size_t)E * 4);                    // nblk*NBKT*4
  int* tot = (int*)(R2 + (size_t)E * 4 + (size_t)nblk * NBKT * 4);
  int* basep = tot + NBKT;

  u16* mean_s = (u16*)R2;                    // [NS][128] bf16
  u16* mean_t = mean_s + (size_t)NS * 128;
  u16* h_s = (u16*)R2;
  u16* h_t = h_s + (size_t)NS * 64;
  float* g_s = (float*)(h_t + (size_t)NT * 64);
  float* g_t = g_s + (size_t)NS * 64;

  // fp8 copies in R2 tail (bytes [ (NS+NT)*384, (NS+NT)*512 ))
  u8* xs_f8 = (u8*)R2 + (size_t)(NS + NT) * 384;
  u8* xt_f8 = xs_f8 + (size_t)NS * 128;

  u16* xs_bf = (u16*)R3;
  u16* xt_bf = xs_bf + (size_t)NS * 128;
  u16* xnew_s = xt_bf + (size_t)NT * 128;
  u16* xnew_t = xnew_s + (size_t)NS * 128;

  u16* Wt1s_l = Wt;
  u16* Wt1s_r = Wt + 16384;
  u16* Wt1t_l = Wt + 32768;
  u16* Wt1t_r = Wt + 49152;
  u16* Wt2A_s = Wt + 65536;  // W2t_l^T (h_s)
  u16* Wt2B_s = Wt + 73728;  // W2s_r^T (g_s)
  u16* Wt2A_t = Wt + 81920;  // W2s_l^T (h_t)
  u16* Wt2B_t = Wt + 90112;  // W2t_r^T (g_t)

  float* z_s = (float*)d_out;
  float* z_t = (float*)d_out + (size_t)NS * 64;

  // conversions (independent of CSR build)
  cvt_bf16_k<<<cdiv(NS * 64, 256), 256, 0, stream>>>(x_s, (u32*)xs_bf, NS * 64);
  cvt_bf16_k<<<cdiv(NT * 64, 256), 256, 0, stream>>>(x_t, (u32*)xt_bf, NT * 64);
  cvt_f8_k<<<cdiv(NS * 32, 256), 256, 0, stream>>>(x_s, (u32*)xs_f8, NS * 32);
  cvt_f8_k<<<cdiv(NT * 32, 256), 256, 0, stream>>>(x_t, (u32*)xt_f8, NT * 32);
  cvtW_k<<<48, 256, 0, stream>>>(W1s_l, W1s_r, W1t_l, W1t_r,
                                 W2t_l, W2s_r, W2s_l, W2t_r, Wt);

  // ----- CSR build: dsts in S (edge list t2s) -----
  hist_k<<<nblk, 256, 0, stream>>>(t2s + E, E, H);
  scanH_k<<<NBKT, 64, 0, stream>>>(H, nblk, tot);
  baseScan_k<<<1, NBKT, 0, stream>>>(tot, basep, E);
  scatter_k<<<nblk, 256, 0, stream>>>(t2s, t2s + E, E, H, basep, bkt);
  finalize_k<<<cdiv(NS, BNODES), 256, 0, stream>>>(bkt, basep, NS, E, rowptr_s, csr_s);

  // ----- CSR build: dsts in T (edge list s2t) -----
  hist_k<<<nblk, 256, 0, stream>>>(s2t + E, E, H);
  scanH_k<<<NBKT, 64, 0, stream>>>(H, nblk, tot);
  baseScan_k<<<1, NBKT, 0, stream>>>(tot, basep, E);
  scatter_k<<<nblk, 256, 0, stream>>>(s2t, s2t + E, E, H, basep, bkt);
  finalize_k<<<cdiv(NT, BNODES), 256, 0, stream>>>(bkt, basep, NT, E, rowptr_t, csr_t);

  // ----- layer 1 -----
  agg128_f8_k<<<cdiv(NS, 4), 256, 0, stream>>>((u32*)xt_f8, rowptr_s, csr_s, NS, (u32*)mean_s);
  agg128_f8_k<<<cdiv(NT, 4), 256, 0, stream>>>((u32*)xs_f8, rowptr_t, csr_t, NT, (u32*)mean_t);
  gemm1_mfma_k<<<cdiv(NS, 128), 256, 0, stream>>>(mean_s, xs_bf, Wt1s_l, Wt1s_r, b1s, xnew_s, NS);
  gemm1_mfma_k<<<cdiv(NT, 128), 256, 0, stream>>>(mean_t, xt_bf, Wt1t_l, Wt1t_r, b1t, xnew_t, NT);

  // ----- layer 2 (transform-first) -----
  gemm2_mfma_k<<<cdiv(NS, 128), 256, 0, stream>>>(xnew_s, Wt2A_s, Wt2B_s, h_s, g_s, NS);
  gemm2_mfma_k<<<cdiv(NT, 128), 256, 0, stream>>>(xnew_t, Wt2A_t, Wt2B_t, h_t, g_t, NT);

  agg64_epi_k<<<cdiv(NS, 4), 256, 0, stream>>>(h_t, rowptr_s, csr_s, NS, g_s, b2s, z_s);
  agg64_epi_k<<<cdiv(NT, 4), 256, 0, stream>>>(h_s, rowptr_t, csr_t, NT, g_t, b2t, z_t);
}

// Round 6
// 305.347 us; speedup vs baseline: 3.2132x; 1.3444x over previous
//
#include <hip/hip_runtime.h>

typedef unsigned int u32;
typedef unsigned short u16;
typedef unsigned char u8;
typedef __attribute__((ext_vector_type(4))) float f32x4;
typedef __attribute__((ext_vector_type(2))) float f32x2;
typedef __attribute__((ext_vector_type(8))) short bf16x8;

static inline int cdiv(int a, int b) { return (a + b - 1) / b; }

#define NBKT 512
#define BSHIFT 7
#define BNODES 128
#define EPB 4096

// ---------- bf16 helpers ----------
__device__ inline u32 pk_bf16(float a, float b) {
  u32 ua = __builtin_bit_cast(u32, a);
  ua += 0x7fffu + ((ua >> 16) & 1u);
  u32 ub = __builtin_bit_cast(u32, b);
  ub += 0x7fffu + ((ub >> 16) & 1u);
  return (ua >> 16) | (ub & 0xffff0000u);
}

// ---------- fused input convert: fp32 -> bf16 + fp8 (4 elems/thread) ----------
__global__ __launch_bounds__(256) void cvt_in_k(const float* __restrict__ xs,
                                                const float* __restrict__ xt,
                                                int nqS, int nqT,
                                                uint2* __restrict__ xsbf,
                                                uint2* __restrict__ xtbf,
                                                u32* __restrict__ xsf8,
                                                u32* __restrict__ xtf8) {
  int i = blockIdx.x * 256 + threadIdx.x;
  const float* src;
  uint2* obf;
  u32* of8;
  int q;
  if (i < nqS) {
    src = xs; obf = xsbf; of8 = xsf8; q = i;
  } else {
    q = i - nqS;
    if (q >= nqT) return;
    src = xt; obf = xtbf; of8 = xtf8;
  }
  float4 v = *reinterpret_cast<const float4*>(src + (size_t)q * 4);
  uint2 b;
  b.x = pk_bf16(v.x, v.y);
  b.y = pk_bf16(v.z, v.w);
  obf[q] = b;
  u32 p = 0;
  p = __builtin_amdgcn_cvt_pk_fp8_f32(v.x, v.y, p, false);
  p = __builtin_amdgcn_cvt_pk_fp8_f32(v.z, v.w, p, true);
  of8[q] = p;
}

// ---------- weights -> transposed bf16, packed buffer ----------
__global__ __launch_bounds__(256) void cvtW_k(const float* __restrict__ W1sl,
                                              const float* __restrict__ W1sr,
                                              const float* __restrict__ W1tl,
                                              const float* __restrict__ W1tr,
                                              const float* __restrict__ W2A_s,
                                              const float* __restrict__ W2B_s,
                                              const float* __restrict__ W2A_t,
                                              const float* __restrict__ W2B_t,
                                              u16* __restrict__ out) {
  int seg = blockIdx.x * 256 + threadIdx.x;  // 12288 total, 8 bf16 per seg
  if (seg >= 12288) return;
  const float* W;
  int ncol, base, local;
  if (seg < 8192) {
    int m = seg >> 11; local = seg & 2047; ncol = 128; base = m * 16384;
    W = m == 0 ? W1sl : m == 1 ? W1sr : m == 2 ? W1tl : W1tr;
  } else {
    int m = (seg - 8192) >> 10; local = (seg - 8192) & 1023; ncol = 64; base = 65536 + m * 8192;
    W = m == 0 ? W2A_s : m == 1 ? W2B_s : m == 2 ? W2A_t : W2B_t;
  }
  int col = local >> 4;
  int k0 = (local & 15) * 8;
  u16 tmp[8];
#pragma unroll
  for (int e = 0; e < 8; ++e) {
    float v = W[(size_t)(k0 + e) * ncol + col];
    tmp[e] = (u16)(pk_bf16(v, 0.f) & 0xffffu);
  }
  *reinterpret_cast<uint4*>(out + (size_t)base + col * 128 + k0) =
      *reinterpret_cast<uint4*>(tmp);
}

// ================= CSR build (both directions fused) =================

__global__ __launch_bounds__(256) void hist2_k(const int* __restrict__ colS,
                                               const int* __restrict__ colT,
                                               int E, int nblk,
                                               int* __restrict__ H_s,
                                               int* __restrict__ H_t) {
  __shared__ int h[NBKT];
  int b = blockIdx.x;
  const int* col;
  int* H;
  if (b < nblk) { col = colS; H = H_s; } else { b -= nblk; col = colT; H = H_t; }
  int t = threadIdx.x;
  for (int i = t; i < NBKT; i += 256) h[i] = 0;
  __syncthreads();
  int base = b * EPB;
  int end = min(base + EPB, E);
  for (int i = base + t; i < end; i += 256) atomicAdd(&h[col[i] >> BSHIFT], 1);
  __syncthreads();
  int* Hrow = H + (size_t)b * NBKT;
  for (int i = t; i < NBKT; i += 256) Hrow[i] = h[i];
}

__global__ __launch_bounds__(64) void scanH2_k(int* __restrict__ H_s,
                                               int* __restrict__ H_t, int nblk,
                                               int* __restrict__ tot_s,
                                               int* __restrict__ tot_t) {
  int b = blockIdx.x;
  int* H;
  int* tot;
  if (b < NBKT) { H = H_s; tot = tot_s; } else { b -= NBKT; H = H_t; tot = tot_t; }
  int lane = threadIdx.x;
  int carry = 0;
  for (int c = 0; c < nblk; c += 64) {
    int idx = c + lane;
    int v = (idx < nblk) ? H[(size_t)idx * NBKT + b] : 0;
    int s = v;
#pragma unroll
    for (int off = 1; off < 64; off <<= 1) {
      int x = __shfl_up(s, off);
      if (lane >= off) s += x;
    }
    if (idx < nblk) H[(size_t)idx * NBKT + b] = s - v + carry;
    carry += __shfl(s, 63);
  }
  if (lane == 0) tot[b] = carry;
}

__global__ __launch_bounds__(NBKT) void base2_k(const int* __restrict__ tot_s,
                                                const int* __restrict__ tot_t,
                                                int* __restrict__ basep_s,
                                                int* __restrict__ basep_t, int E) {
  __shared__ int sm[NBKT];
  const int* tot = blockIdx.x == 0 ? tot_s : tot_t;
  int* basep = blockIdx.x == 0 ? basep_s : basep_t;
  int t = threadIdx.x;
  int v = tot[t];
  sm[t] = v;
  __syncthreads();
  for (int off = 1; off < NBKT; off <<= 1) {
    int x = (t >= off) ? sm[t - off] : 0;
    __syncthreads();
    if (t >= off) sm[t] += x;
    __syncthreads();
  }
  basep[t] = sm[t] - v;
  if (t == NBKT - 1) basep[NBKT] = E;
}

__global__ __launch_bounds__(256) void scatter2_k(const int* __restrict__ rowS,
                                                  const int* __restrict__ colS,
                                                  const int* __restrict__ rowT,
                                                  const int* __restrict__ colT,
                                                  int E, int nblk,
                                                  const int* __restrict__ H_s,
                                                  const int* __restrict__ H_t,
                                                  const int* __restrict__ basep_s,
                                                  const int* __restrict__ basep_t,
                                                  u32* __restrict__ bkt_s,
                                                  u32* __restrict__ bkt_t) {
  __shared__ int cur[NBKT];
  int b = blockIdx.x;
  const int *row, *col, *H, *basep;
  u32* bkt;
  if (b < nblk) {
    row = rowS; col = colS; H = H_s; basep = basep_s; bkt = bkt_s;
  } else {
    b -= nblk; row = rowT; col = colT; H = H_t; basep = basep_t; bkt = bkt_t;
  }
  int t = threadIdx.x;
  const int* Hrow = H + (size_t)b * NBKT;
  for (int i = t; i < NBKT; i += 256) cur[i] = basep[i] + Hrow[i];
  __syncthreads();
  int base = b * EPB;
  int end = min(base + EPB, E);
  for (int i = base + t; i < end; i += 256) {
    int c = col[i];
    int p = atomicAdd(&cur[c >> BSHIFT], 1);
    bkt[p] = ((u32)row[i] << BSHIFT) | (u32)(c & (BNODES - 1));
  }
}

__global__ __launch_bounds__(256) void fin2_k(const u32* __restrict__ bkt_s,
                                              const u32* __restrict__ bkt_t,
                                              const int* __restrict__ basep_s,
                                              const int* __restrict__ basep_t,
                                              int NS, int NT, int Etot,
                                              int* __restrict__ rowptr_s,
                                              int* __restrict__ rowptr_t,
                                              int* __restrict__ csr_s,
                                              int* __restrict__ csr_t) {
  __shared__ int cnt[BNODES];
  __shared__ int excl[BNODES];
  int b = blockIdx.x;
  const u32* bkt;
  const int* basep;
  int* rowptr;
  int* csr;
  int N;
  if (b < NBKT) {
    bkt = bkt_s; basep = basep_s; rowptr = rowptr_s; csr = csr_s; N = NS;
  } else {
    b -= NBKT; bkt = bkt_t; basep = basep_t; rowptr = rowptr_t; csr = csr_t; N = NT;
  }
  int t = threadIdx.x;
  int node0 = b << BSHIFT;
  int rs = basep[b], re = basep[b + 1];
  if (t < BNODES) cnt[t] = 0;
  __syncthreads();
  for (int i = rs + t; i < re; i += 256) {
    atomicAdd(&cnt[bkt[i] & (BNODES - 1)], 1);
  }
  __syncthreads();
  if (t < BNODES) excl[t] = cnt[t];
  __syncthreads();
  for (int off = 1; off < BNODES; off <<= 1) {
    int x = 0;
    if (t < BNODES && t >= off) x = excl[t - off];
    __syncthreads();
    if (t < BNODES && t >= off) excl[t] += x;
    __syncthreads();
  }
  if (t < BNODES) {
    int node = node0 + t;
    int start = rs + excl[t] - cnt[t];
    if (node < N) rowptr[node] = start;
    cnt[t] = start;
  }
  if (b == 0 && t == 0) rowptr[N] = Etot;
  __syncthreads();
  for (int i = rs + t; i < re; i += 256) {
    u32 p = bkt[i];
    int pos = atomicAdd(&cnt[p & (BNODES - 1)], 1);
    csr[pos] = (int)(p >> BSHIFT);
  }
}

// ---------------- layer-1 mean agg (fp8, 128 feats): 4 edges/wave, unroll 2 ----------------
// edge row = 128 fp8 = 32 u32; 16 lanes x uint2 per edge. Both directions fused.

__global__ __launch_bounds__(256) void agg128_f8_dual(
    const u32* __restrict__ xs_f8, const u32* __restrict__ xt_f8,
    const int* __restrict__ rowptr_s, const int* __restrict__ csr_s,
    const int* __restrict__ rowptr_t, const int* __restrict__ csr_t,
    int NS, int NT, u32* __restrict__ mean_s, u32* __restrict__ mean_t) {
  int nbS = (NS + 3) >> 2;
  int b = blockIdx.x;
  const u32* xf8;
  const int *rowptr, *csr;
  u32* outm;
  int node;
  if (b < nbS) {
    xf8 = xt_f8; rowptr = rowptr_s; csr = csr_s; outm = mean_s;
    node = b * 4 + (threadIdx.x >> 6);
    if (node >= NS) return;
  } else {
    xf8 = xs_f8; rowptr = rowptr_t; csr = csr_t; outm = mean_t;
    node = (b - nbS) * 4 + (threadIdx.x >> 6);
    if (node >= NT) return;
  }
  int lane = threadIdx.x & 63;
  int eg = lane >> 4;  // edge slot 0..3
  int fl = lane & 15;  // uint2 chunk (8 fp8)
  int s = rowptr[node], e = rowptr[node + 1];
  f32x2 a0 = {0.f, 0.f}, a1 = {0.f, 0.f}, a2 = {0.f, 0.f}, a3 = {0.f, 0.f};
  int i = s + eg;
  for (; i + 4 < e; i += 8) {
    int c0 = csr[i], c1 = csr[i + 4];
    uint2 v0 = *reinterpret_cast<const uint2*>(xf8 + (size_t)c0 * 32 + fl * 2);
    uint2 v1 = *reinterpret_cast<const uint2*>(xf8 + (size_t)c1 * 32 + fl * 2);
    a0 += __builtin_amdgcn_cvt_pk_f32_fp8(v0.x, false);
    a1 += __builtin_amdgcn_cvt_pk_f32_fp8(v0.x, true);
    a2 += __builtin_amdgcn_cvt_pk_f32_fp8(v0.y, false);
    a3 += __builtin_amdgcn_cvt_pk_f32_fp8(v0.y, true);
    a0 += __builtin_amdgcn_cvt_pk_f32_fp8(v1.x, false);
    a1 += __builtin_amdgcn_cvt_pk_f32_fp8(v1.x, true);
    a2 += __builtin_amdgcn_cvt_pk_f32_fp8(v1.y, false);
    a3 += __builtin_amdgcn_cvt_pk_f32_fp8(v1.y, true);
  }
  for (; i < e; i += 4) {
    int c0 = csr[i];
    uint2 v0 = *reinterpret_cast<const uint2*>(xf8 + (size_t)c0 * 32 + fl * 2);
    a0 += __builtin_amdgcn_cvt_pk_f32_fp8(v0.x, false);
    a1 += __builtin_amdgcn_cvt_pk_f32_fp8(v0.x, true);
    a2 += __builtin_amdgcn_cvt_pk_f32_fp8(v0.y, false);
    a3 += __builtin_amdgcn_cvt_pk_f32_fp8(v0.y, true);
  }
  // reduce over 4 edge groups (lanes fl, fl+16, fl+32, fl+48)
#pragma unroll
  for (int m = 16; m <= 32; m <<= 1) {
    a0.x += __shfl_xor(a0.x, m); a0.y += __shfl_xor(a0.y, m);
    a1.x += __shfl_xor(a1.x, m); a1.y += __shfl_xor(a1.y, m);
    a2.x += __shfl_xor(a2.x, m); a2.y += __shfl_xor(a2.y, m);
    a3.x += __shfl_xor(a3.x, m); a3.y += __shfl_xor(a3.y, m);
  }
  if (lane < 16) {
    float inv = (e > s) ? 1.f / (float)(e - s) : 0.f;
    uint4 p;
    p.x = pk_bf16(a0.x * inv, a0.y * inv);
    p.y = pk_bf16(a1.x * inv, a1.y * inv);
    p.z = pk_bf16(a2.x * inv, a2.y * inv);
    p.w = pk_bf16(a3.x * inv, a3.y * inv);
    *reinterpret_cast<uint4*>(outm + (size_t)node * 64 + fl * 4) = p;
  }
}

// ---------------- layer-2 mean agg (fp8 h, 64 feats) + epilogue: 4 edges/wave ----------------
// edge row = 64 fp8 = 16 u32; 16 lanes x u32 per edge. z = mean + g + bias. Fused dirs.

__global__ __launch_bounds__(256) void agg64_f8_dual(
    const u32* __restrict__ hs_f8, const u32* __restrict__ ht_f8,
    const int* __restrict__ rowptr_s, const int* __restrict__ csr_s,
    const int* __restrict__ rowptr_t, const int* __restrict__ csr_t,
    int NS, int NT,
    const float* __restrict__ g_s, const float* __restrict__ g_t,
    const float* __restrict__ b2s, const float* __restrict__ b2t,
    float* __restrict__ z_s, float* __restrict__ z_t) {
  int nbS = (NS + 3) >> 2;
  int b = blockIdx.x;
  const u32* hf8;
  const int *rowptr, *csr;
  const float *g, *bias;
  float* z;
  int node;
  if (b < nbS) {
    hf8 = ht_f8; rowptr = rowptr_s; csr = csr_s; g = g_s; bias = b2s; z = z_s;
    node = b * 4 + (threadIdx.x >> 6);
    if (node >= NS) return;
  } else {
    hf8 = hs_f8; rowptr = rowptr_t; csr = csr_t; g = g_t; bias = b2t; z = z_t;
    node = (b - nbS) * 4 + (threadIdx.x >> 6);
    if (node >= NT) return;
  }
  int lane = threadIdx.x & 63;
  int eg = lane >> 4;
  int fl = lane & 15;  // u32 chunk (4 fp8)
  int s = rowptr[node], e = rowptr[node + 1];
  f32x2 a0 = {0.f, 0.f}, a1 = {0.f, 0.f};
  int i = s + eg;
  for (; i + 4 < e; i += 8) {
    int c0 = csr[i], c1 = csr[i + 4];
    u32 v0 = hf8[(size_t)c0 * 16 + fl];
    u32 v1 = hf8[(size_t)c1 * 16 + fl];
    a0 += __builtin_amdgcn_cvt_pk_f32_fp8(v0, false);
    a1 += __builtin_amdgcn_cvt_pk_f32_fp8(v0, true);
    a0 += __builtin_amdgcn_cvt_pk_f32_fp8(v1, false);
    a1 += __builtin_amdgcn_cvt_pk_f32_fp8(v1, true);
  }
  for (; i < e; i += 4) {
    u32 v0 = hf8[(size_t)csr[i] * 16 + fl];
    a0 += __builtin_amdgcn_cvt_pk_f32_fp8(v0, false);
    a1 += __builtin_amdgcn_cvt_pk_f32_fp8(v0, true);
  }
#pragma unroll
  for (int m = 16; m <= 32; m <<= 1) {
    a0.x += __shfl_xor(a0.x, m); a0.y += __shfl_xor(a0.y, m);
    a1.x += __shfl_xor(a1.x, m); a1.y += __shfl_xor(a1.y, m);
  }
  if (lane < 16) {
    float inv = (e > s) ? 1.f / (float)(e - s) : 0.f;
    float4 gv = *reinterpret_cast<const float4*>(g + (size_t)node * 64 + fl * 4);
    float4 bv = *reinterpret_cast<const float4*>(bias + fl * 4);
    float4 r;
    r.x = a0.x * inv + gv.x + bv.x;
    r.y = a0.y * inv + gv.y + bv.y;
    r.z = a1.x * inv + gv.z + bv.z;
    r.w = a1.y * inv + gv.w + bv.w;
    *reinterpret_cast<float4*>(z + (size_t)node * 64 + fl * 4) = r;
  }
}

// ---------------- layer-1 MFMA GEMM (dirs fused): out_bf16 = [A0|A1]@[W0;W1]+bias ----------------

__global__ __launch_bounds__(256) void gemm1_dual_k(
    const u16* __restrict__ mean_s, const u16* __restrict__ xs_bf,
    const u16* __restrict__ mean_t, const u16* __restrict__ xt_bf,
    const u16* __restrict__ Wt_s0, const u16* __restrict__ Wt_s1,
    const u16* __restrict__ Wt_t0, const u16* __restrict__ Wt_t1,
    const float* __restrict__ b1s, const float* __restrict__ b1t,
    u16* __restrict__ xnew_s, u16* __restrict__ xnew_t, int NS, int NT) {
  int nb1 = (NS + 127) >> 7;
  int b = blockIdx.x;
  const u16 *A0, *A1, *Wt0, *Wt1;
  const float* bias;
  u16* out;
  int M, rowBase;
  if (b < nb1) {
    A0 = mean_s; A1 = xs_bf; Wt0 = Wt_s0; Wt1 = Wt_s1; bias = b1s; out = xnew_s;
    M = NS; rowBase = b * 128;
  } else {
    A0 = mean_t; A1 = xt_bf; Wt0 = Wt_t0; Wt1 = Wt_t1; bias = b1t; out = xnew_t;
    M = NT; rowBase = (b - nb1) * 128;
  }
  const int lane = threadIdx.x & 63;
  const int wid = threadIdx.x >> 6;
  const int r16 = lane & 15;
  const int kg = lane >> 4;
  rowBase += wid * 32;

  f32x4 acc[2][8];
#pragma unroll
  for (int i = 0; i < 2; ++i)
#pragma unroll
    for (int j = 0; j < 8; ++j) acc[i][j] = (f32x4){0.f, 0.f, 0.f, 0.f};

  const int r0 = min(rowBase + r16, M - 1);
  const int r1 = min(rowBase + 16 + r16, M - 1);

#pragma unroll
  for (int ch = 0; ch < 8; ++ch) {
    const u16* A = (ch < 4) ? A0 : A1;
    const u16* Wt = (ch < 4) ? Wt0 : Wt1;
    const int koff = (ch & 3) * 32 + kg * 8;
    bf16x8 x0 = *reinterpret_cast<const bf16x8*>(A + (size_t)r0 * 128 + koff);
    bf16x8 x1 = *reinterpret_cast<const bf16x8*>(A + (size_t)r1 * 128 + koff);
#pragma unroll
    for (int cb = 0; cb < 8; ++cb) {
      bf16x8 w = *reinterpret_cast<const bf16x8*>(Wt + (size_t)(cb * 16 + r16) * 128 + koff);
      acc[0][cb] = __builtin_amdgcn_mfma_f32_16x16x32_bf16(w, x0, acc[0][cb], 0, 0, 0);
      acc[1][cb] = __builtin_amdgcn_mfma_f32_16x16x32_bf16(w, x1, acc[1][cb], 0, 0, 0);
    }
  }

#pragma unroll
  for (int cb = 0; cb < 8; ++cb) {
    float4 bv = *reinterpret_cast<const float4*>(bias + cb * 16 + kg * 4);
#pragma unroll
    for (int rb = 0; rb < 2; ++rb) {
      int row = rowBase + rb * 16 + r16;
      if (row < M) {
        f32x4 a = acc[rb][cb];
        uint2 p;
        p.x = pk_bf16(a[0] + bv.x, a[1] + bv.y);
        p.y = pk_bf16(a[2] + bv.z, a[3] + bv.w);
        *reinterpret_cast<uint2*>(out + (size_t)row * 128 + cb * 16 + kg * 4) = p;
      }
    }
  }
}

// ---------------- layer-2 MFMA GEMM (dirs fused): h_fp8 = X@Wa, g_f32 = X@Wb ----------------

__global__ __launch_bounds__(256) void gemm2_dual_k(
    const u16* __restrict__ xnew_s, const u16* __restrict__ xnew_t,
    const u16* __restrict__ WtA_s, const u16* __restrict__ WtB_s,
    const u16* __restrict__ WtA_t, const u16* __restrict__ WtB_t,
    u32* __restrict__ hs_f8, u32* __restrict__ ht_f8,
    float* __restrict__ g_s, float* __restrict__ g_t, int NS, int NT) {
  int nb1 = (NS + 127) >> 7;
  int b = blockIdx.x;
  const u16 *X, *WtA, *WtB;
  u32* h;
  float* g;
  int M, rowBase;
  if (b < nb1) {
    X = xnew_s; WtA = WtA_s; WtB = WtB_s; h = hs_f8; g = g_s; M = NS; rowBase = b * 128;
  } else {
    X = xnew_t; WtA = WtA_t; WtB = WtB_t; h = ht_f8; g = g_t; M = NT;
    rowBase = (b - nb1) * 128;
  }
  const int lane = threadIdx.x & 63;
  const int wid = threadIdx.x >> 6;
  const int r16 = lane & 15;
  const int kg = lane >> 4;
  rowBase += wid * 32;

  f32x4 acc[2][8];
#pragma unroll
  for (int i = 0; i < 2; ++i)
#pragma unroll
    for (int j = 0; j < 8; ++j) acc[i][j] = (f32x4){0.f, 0.f, 0.f, 0.f};

  const int r0 = min(rowBase + r16, M - 1);
  const int r1 = min(rowBase + 16 + r16, M - 1);

#pragma unroll
  for (int ch = 0; ch < 4; ++ch) {
    const int koff = ch * 32 + kg * 8;
    bf16x8 x0 = *reinterpret_cast<const bf16x8*>(X + (size_t)r0 * 128 + koff);
    bf16x8 x1 = *reinterpret_cast<const bf16x8*>(X + (size_t)r1 * 128 + koff);
#pragma unroll
    for (int cb = 0; cb < 8; ++cb) {
      const u16* Wt = (cb < 4) ? WtA : WtB;
      bf16x8 w = *reinterpret_cast<const bf16x8*>(Wt + (size_t)((cb & 3) * 16 + r16) * 128 + koff);
      acc[0][cb] = __builtin_amdgcn_mfma_f32_16x16x32_bf16(w, x0, acc[0][cb], 0, 0, 0);
      acc[1][cb] = __builtin_amdgcn_mfma_f32_16x16x32_bf16(w, x1, acc[1][cb], 0, 0, 0);
    }
  }

#pragma unroll
  for (int cb = 0; cb < 8; ++cb) {
#pragma unroll
    for (int rb = 0; rb < 2; ++rb) {
      int row = rowBase + rb * 16 + r16;
      if (row < M) {
        f32x4 a = acc[rb][cb];
        if (cb < 4) {
          u32 p = 0;
          p = __builtin_amdgcn_cvt_pk_fp8_f32(a[0], a[1], p, false);
          p = __builtin_amdgcn_cvt_pk_fp8_f32(a[2], a[3], p, true);
          h[(size_t)row * 16 + cb * 4 + kg] = p;
        } else {
          *reinterpret_cast<f32x4*>(g + (size_t)row * 64 + (cb - 4) * 16 + kg * 4) = a;
        }
      }
    }
  }
}

// ---------------- launch ----------------

extern "C" void kernel_launch(void* const* d_in, const int* in_sizes, int n_in,
                              void* d_out, int out_size, void* d_ws, size_t ws_size,
                              hipStream_t stream) {
  const float* x_s = (const float*)d_in[0];
  const float* x_t = (const float*)d_in[1];
  const int* s2t = (const int*)d_in[2];
  const int* t2s = (const int*)d_in[3];
  const float* W1s_l = (const float*)d_in[4];
  const float* W1s_r = (const float*)d_in[5];
  const float* b1s = (const float*)d_in[6];
  const float* W1t_l = (const float*)d_in[7];
  const float* W1t_r = (const float*)d_in[8];
  const float* b1t = (const float*)d_in[9];
  const float* W2s_l = (const float*)d_in[10];
  const float* W2s_r = (const float*)d_in[11];
  const float* b2s = (const float*)d_in[12];
  const float* W2t_l = (const float*)d_in[13];
  const float* W2t_r = (const float*)d_in[14];
  const float* b2t = (const float*)d_in[15];

  const int NS = in_sizes[0] / 128;
  const int NT = in_sizes[1] / 128;
  const int E = in_sizes[2] / 2;

  char* ws = (char*)d_ws;
  size_t off = 0;
  auto alloc = [&](size_t bytes) -> void* {
    void* p = ws + off;
    off = (off + bytes + 255) & ~(size_t)255;
    return p;
  };

  int* rowptr_s = (int*)alloc((size_t)(NS + 1) * 4);
  int* rowptr_t = (int*)alloc((size_t)(NT + 1) * 4);
  int* csr_s = (int*)alloc((size_t)E * 4);
  int* csr_t = (int*)alloc((size_t)E * 4);
  u16* Wt = (u16*)alloc(98304 * 2);

  // R2 ((NS+NT)*512 B): head [0,384B/node) = CSR temps -> mean_bf -> h_f8/g;
  //                     tail [384,512) = fp8 x copies
  char* R2 = (char*)alloc((size_t)(NS + NT) * 512);
  // R3: xs_bf|xt_bf|xnew_s|xnew_t (all bf16)
  char* R3 = (char*)alloc((size_t)(NS + NT) * 512);

  const int nblk = cdiv(E, EPB);

  // CSR-build temps (head of R2; dead before mean is written)
  u32* bkt_s = (u32*)R2;
  u32* bkt_t = bkt_s + E;
  int* H_s = (int*)(bkt_t + E);
  int* H_t = H_s + (size_t)nblk * NBKT;
  int* tot_s = H_t + (size_t)nblk * NBKT;
  int* basep_s = tot_s + NBKT;
  int* tot_t = basep_s + NBKT + 1;
  int* basep_t = tot_t + NBKT;

  u16* mean_s = (u16*)R2;  // [NS][128] bf16
  u16* mean_t = mean_s + (size_t)NS * 128;
  u32* hs_f8 = (u32*)R2;   // [NS][16] u32 (64 fp8)
  u32* ht_f8 = hs_f8 + (size_t)NS * 16;
  float* g_s = (float*)(ht_f8 + (size_t)NT * 16);
  float* g_t = g_s + (size_t)NS * 64;

  u32* xs_f8 = (u32*)(R2 + (size_t)(NS + NT) * 384);  // [NS][32] u32
  u32* xt_f8 = xs_f8 + (size_t)NS * 32;

  u16* xs_bf = (u16*)R3;
  u16* xt_bf = xs_bf + (size_t)NS * 128;
  u16* xnew_s = xt_bf + (size_t)NT * 128;
  u16* xnew_t = xnew_s + (size_t)NS * 128;

  u16* Wt1s_l = Wt;
  u16* Wt1s_r = Wt + 16384;
  u16* Wt1t_l = Wt + 32768;
  u16* Wt1t_r = Wt + 49152;
  u16* Wt2A_s = Wt + 65536;  // W2t_l^T (h_s)
  u16* Wt2B_s = Wt + 73728;  // W2s_r^T (g_s)
  u16* Wt2A_t = Wt + 81920;  // W2s_l^T (h_t)
  u16* Wt2B_t = Wt + 90112;  // W2t_r^T (g_t)

  float* z_s = (float*)d_out;
  float* z_t = (float*)d_out + (size_t)NS * 64;

  // input conversions (bf16 + fp8 in one pass)
  const int nqS = NS * 32, nqT = NT * 32;
  cvt_in_k<<<cdiv(nqS + nqT, 256), 256, 0, stream>>>(
      x_s, x_t, nqS, nqT, (uint2*)xs_bf, (uint2*)xt_bf, xs_f8, xt_f8);
  cvtW_k<<<48, 256, 0, stream>>>(W1s_l, W1s_r, W1t_l, W1t_r,
                                 W2t_l, W2s_r, W2s_l, W2t_r, Wt);

  // ----- CSR build, both directions -----
  hist2_k<<<2 * nblk, 256, 0, stream>>>(t2s + E, s2t + E, E, nblk, H_s, H_t);
  scanH2_k<<<2 * NBKT, 64, 0, stream>>>(H_s, H_t, nblk, tot_s, tot_t);
  base2_k<<<2, NBKT, 0, stream>>>(tot_s, tot_t, basep_s, basep_t, E);
  scatter2_k<<<2 * nblk, 256, 0, stream>>>(t2s, t2s + E, s2t, s2t + E, E, nblk,
                                           H_s, H_t, basep_s, basep_t, bkt_s, bkt_t);
  fin2_k<<<2 * NBKT, 256, 0, stream>>>(bkt_s, bkt_t, basep_s, basep_t, NS, NT, E,
                                       rowptr_s, rowptr_t, csr_s, csr_t);

  // ----- layer 1 -----
  agg128_f8_dual<<<cdiv(NS, 4) + cdiv(NT, 4), 256, 0, stream>>>(
      xs_f8, xt_f8, rowptr_s, csr_s, rowptr_t, csr_t, NS, NT,
      (u32*)mean_s, (u32*)mean_t);
  gemm1_dual_k<<<cdiv(NS, 128) + cdiv(NT, 128), 256, 0, stream>>>(
      mean_s, xs_bf, mean_t, xt_bf, Wt1s_l, Wt1s_r, Wt1t_l, Wt1t_r,
      b1s, b1t, xnew_s, xnew_t, NS, NT);

  // ----- layer 2 (transform-first) -----
  gemm2_dual_k<<<cdiv(NS, 128) + cdiv(NT, 128), 256, 0, stream>>>(
      xnew_s, xnew_t, Wt2A_s, Wt2B_s, Wt2A_t, Wt2B_t, hs_f8, ht_f8, g_s, g_t, NS, NT);
  agg64_f8_dual<<<cdiv(NS, 4) + cdiv(NT, 4), 256, 0, stream>>>(
      hs_f8, ht_f8, rowptr_s, csr_s, rowptr_t, csr_t, NS, NT,
      g_s, g_t, b2s, b2t, z_s, z_t);
}

// Round 7
// 266.321 us; speedup vs baseline: 3.6840x; 1.1465x over previous
//
#include <hip/hip_runtime.h>

typedef unsigned int u32;
typedef unsigned short u16;
typedef __attribute__((ext_vector_type(4))) float f32x4;
typedef __attribute__((ext_vector_type(2))) float f32x2;
typedef __attribute__((ext_vector_type(8))) short bf16x8;

static inline int cdiv(int a, int b) { return (a + b - 1) / b; }

#define NBKT 512
#define BSHIFT 7
#define BNODES 128
#define EPB 4096
#define CAP 5120  // per-bucket capacity; mean fill 4096, sigma 64 -> 16 sigma headroom

// ---------- bf16 helpers ----------
__device__ inline u32 pk_bf16(float a, float b) {
  u32 ua = __builtin_bit_cast(u32, a);
  ua += 0x7fffu + ((ua >> 16) & 1u);
  u32 ub = __builtin_bit_cast(u32, b);
  ub += 0x7fffu + ((ub >> 16) & 1u);
  return (ua >> 16) | (ub & 0xffff0000u);
}

// ---------- fp32 -> fp8 e4m3 (4 elems/thread), both sides fused ----------
__global__ __launch_bounds__(256) void cvt_f8_k(const float* __restrict__ xs,
                                                const float* __restrict__ xt,
                                                int n4S, int n4T,
                                                u32* __restrict__ xsf8,
                                                u32* __restrict__ xtf8) {
  int i = blockIdx.x * 256 + threadIdx.x;
  const float* src;
  u32* dst;
  int q;
  if (i < n4S) {
    src = xs; dst = xsf8; q = i;
  } else {
    q = i - n4S;
    if (q >= n4T) return;
    src = xt; dst = xtf8;
  }
  float4 v = *reinterpret_cast<const float4*>(src + (size_t)q * 4);
  u32 p = 0;
  p = __builtin_amdgcn_cvt_pk_fp8_f32(v.x, v.y, p, false);
  p = __builtin_amdgcn_cvt_pk_fp8_f32(v.z, v.w, p, true);
  dst[q] = p;
}

// ---------- weights -> transposed bf16, packed buffer ----------
__global__ __launch_bounds__(256) void cvtW_k(const float* __restrict__ W1sl,
                                              const float* __restrict__ W1sr,
                                              const float* __restrict__ W1tl,
                                              const float* __restrict__ W1tr,
                                              const float* __restrict__ W2A_s,
                                              const float* __restrict__ W2B_s,
                                              const float* __restrict__ W2A_t,
                                              const float* __restrict__ W2B_t,
                                              u16* __restrict__ out) {
  int seg = blockIdx.x * 256 + threadIdx.x;  // 12288 total, 8 bf16 per seg
  if (seg >= 12288) return;
  const float* W;
  int ncol, base, local;
  if (seg < 8192) {
    int m = seg >> 11; local = seg & 2047; ncol = 128; base = m * 16384;
    W = m == 0 ? W1sl : m == 1 ? W1sr : m == 2 ? W1tl : W1tr;
  } else {
    int m = (seg - 8192) >> 10; local = (seg - 8192) & 1023; ncol = 64; base = 65536 + m * 8192;
    W = m == 0 ? W2A_s : m == 1 ? W2B_s : m == 2 ? W2A_t : W2B_t;
  }
  int col = local >> 4;
  int k0 = (local & 15) * 8;
  u16 tmp[8];
#pragma unroll
  for (int e = 0; e < 8; ++e) {
    float v = W[(size_t)(k0 + e) * ncol + col];
    tmp[e] = (u16)(pk_bf16(v, 0.f) & 0xffffu);
  }
  *reinterpret_cast<uint4*>(out + (size_t)base + col * 128 + k0) =
      *reinterpret_cast<uint4*>(tmp);
}

// ================= bucket scatter: hist + atomic reserve + place, one kernel =================
// bkt entry = (src << 7) | (dst & 127); bucket b region = bkt + b*CAP; gcur[b] = fill count.

__global__ __launch_bounds__(256) void scatfuse_k(const int* __restrict__ rowS,
                                                  const int* __restrict__ colS,
                                                  const int* __restrict__ rowT,
                                                  const int* __restrict__ colT,
                                                  int E, int nblk,
                                                  int* __restrict__ gcur,
                                                  u32* __restrict__ bktS,
                                                  u32* __restrict__ bktT) {
  __shared__ int h[NBKT];
  __shared__ int pos[NBKT];
  int b = blockIdx.x;
  const int *row, *col;
  u32* bkt;
  int* gc;
  if (b < nblk) {
    row = rowS; col = colS; bkt = bktS; gc = gcur;
  } else {
    b -= nblk; row = rowT; col = colT; bkt = bktT; gc = gcur + NBKT;
  }
  int t = threadIdx.x;
  for (int i = t; i < NBKT; i += 256) h[i] = 0;
  __syncthreads();
  int base = b * EPB, end = min(base + EPB, E);
  for (int i = base + t; i < end; i += 256) atomicAdd(&h[col[i] >> BSHIFT], 1);
  __syncthreads();
  for (int i = t; i < NBKT; i += 256) {
    int c = h[i];
    pos[i] = c ? atomicAdd(&gc[i], c) : 0;
  }
  __syncthreads();
  for (int i = base + t; i < end; i += 256) {
    int c = col[i];
    int bi = c >> BSHIFT;
    int p = atomicAdd(&pos[bi], 1);
    bkt[(size_t)bi * CAP + p] = ((u32)row[i] << BSHIFT) | (u32)(c & (BNODES - 1));
  }
}

// ================= layer-1 agg: per-bucket LDS mini-CSR + fp8 gather =================
// one 16-lane group per node (no cross-lane reduce); row = 128 fp8 = 32 u32, uint2/lane.

__global__ __launch_bounds__(256) void agg128B_k(const u32* __restrict__ xs_f8,
                                                 const u32* __restrict__ xt_f8,
                                                 const u32* __restrict__ bktS,
                                                 const u32* __restrict__ bktT,
                                                 const int* __restrict__ gcur,
                                                 int NS, int NT,
                                                 u32* __restrict__ mean_s,
                                                 u32* __restrict__ mean_t) {
  __shared__ u32 srcs[CAP];
  __shared__ int cnt[BNODES], excl[BNODES], st[BNODES], cur[BNODES];
  int nbkS = (NS + BNODES - 1) >> BSHIFT;
  int b = blockIdx.x;
  const u32 *xf8, *bkt;
  u32* outm;
  int N, ec;
  if (b < nbkS) {
    xf8 = xt_f8; bkt = bktS + (size_t)b * CAP; ec = gcur[b]; outm = mean_s; N = NS;
  } else {
    b -= nbkS;
    xf8 = xs_f8; bkt = bktT + (size_t)b * CAP; ec = gcur[NBKT + b]; outm = mean_t; N = NT;
  }
  int node0 = b << BSHIFT;
  int t = threadIdx.x;
  if (t < BNODES) cnt[t] = 0;
  __syncthreads();
  for (int i = t; i < ec; i += 256) atomicAdd(&cnt[bkt[i] & (BNODES - 1)], 1);
  __syncthreads();
  if (t < BNODES) excl[t] = cnt[t];
  __syncthreads();
  for (int off = 1; off < BNODES; off <<= 1) {
    int x = 0;
    if (t < BNODES && t >= off) x = excl[t - off];
    __syncthreads();
    if (t < BNODES && t >= off) excl[t] += x;
    __syncthreads();
  }
  if (t < BNODES) {
    int s0 = excl[t] - cnt[t];
    st[t] = s0;
    cur[t] = s0;
  }
  __syncthreads();
  for (int i = t; i < ec; i += 256) {
    u32 p = bkt[i];
    int ps = atomicAdd(&cur[p & (BNODES - 1)], 1);
    srcs[ps] = p >> BSHIFT;
  }
  __syncthreads();

  int gid = t >> 4, fl = t & 15;
  for (int n = gid; n < BNODES; n += 16) {
    int node = node0 + n;
    int s = st[n], deg = cnt[n], e = s + deg;
    f32x2 a0 = {0.f, 0.f}, a1 = {0.f, 0.f}, a2 = {0.f, 0.f}, a3 = {0.f, 0.f};
    int i = s;
    for (; i + 4 <= e; i += 4) {
      int c0 = srcs[i], c1 = srcs[i + 1], c2 = srcs[i + 2], c3 = srcs[i + 3];
      uint2 v0 = *reinterpret_cast<const uint2*>(xf8 + (size_t)c0 * 32 + fl * 2);
      uint2 v1 = *reinterpret_cast<const uint2*>(xf8 + (size_t)c1 * 32 + fl * 2);
      uint2 v2 = *reinterpret_cast<const uint2*>(xf8 + (size_t)c2 * 32 + fl * 2);
      uint2 v3 = *reinterpret_cast<const uint2*>(xf8 + (size_t)c3 * 32 + fl * 2);
      a0 += __builtin_amdgcn_cvt_pk_f32_fp8(v0.x, false);
      a1 += __builtin_amdgcn_cvt_pk_f32_fp8(v0.x, true);
      a2 += __builtin_amdgcn_cvt_pk_f32_fp8(v0.y, false);
      a3 += __builtin_amdgcn_cvt_pk_f32_fp8(v0.y, true);
      a0 += __builtin_amdgcn_cvt_pk_f32_fp8(v1.x, false);
      a1 += __builtin_amdgcn_cvt_pk_f32_fp8(v1.x, true);
      a2 += __builtin_amdgcn_cvt_pk_f32_fp8(v1.y, false);
      a3 += __builtin_amdgcn_cvt_pk_f32_fp8(v1.y, true);
      a0 += __builtin_amdgcn_cvt_pk_f32_fp8(v2.x, false);
      a1 += __builtin_amdgcn_cvt_pk_f32_fp8(v2.x, true);
      a2 += __builtin_amdgcn_cvt_pk_f32_fp8(v2.y, false);
      a3 += __builtin_amdgcn_cvt_pk_f32_fp8(v2.y, true);
      a0 += __builtin_amdgcn_cvt_pk_f32_fp8(v3.x, false);
      a1 += __builtin_amdgcn_cvt_pk_f32_fp8(v3.x, true);
      a2 += __builtin_amdgcn_cvt_pk_f32_fp8(v3.y, false);
      a3 += __builtin_amdgcn_cvt_pk_f32_fp8(v3.y, true);
    }
    for (; i < e; ++i) {
      int c0 = srcs[i];
      uint2 v0 = *reinterpret_cast<const uint2*>(xf8 + (size_t)c0 * 32 + fl * 2);
      a0 += __builtin_amdgcn_cvt_pk_f32_fp8(v0.x, false);
      a1 += __builtin_amdgcn_cvt_pk_f32_fp8(v0.x, true);
      a2 += __builtin_amdgcn_cvt_pk_f32_fp8(v0.y, false);
      a3 += __builtin_amdgcn_cvt_pk_f32_fp8(v0.y, true);
    }
    if (node < N) {
      float inv = deg > 0 ? 1.f / (float)deg : 0.f;
      uint4 p;
      p.x = pk_bf16(a0.x * inv, a0.y * inv);
      p.y = pk_bf16(a1.x * inv, a1.y * inv);
      p.z = pk_bf16(a2.x * inv, a2.y * inv);
      p.w = pk_bf16(a3.x * inv, a3.y * inv);
      *reinterpret_cast<uint4*>(outm + (size_t)node * 64 + fl * 4) = p;
    }
  }
}

// ================= layer-2 agg + epilogue: per-bucket LDS mini-CSR, fp8 h gather =================
// row = 64 fp8 = 16 u32, 1 u32/lane; z = mean + g + bias.

__global__ __launch_bounds__(256) void agg64B_k(const u32* __restrict__ hs_f8,
                                                const u32* __restrict__ ht_f8,
                                                const u32* __restrict__ bktS,
                                                const u32* __restrict__ bktT,
                                                const int* __restrict__ gcur,
                                                int NS, int NT,
                                                const float* __restrict__ g_s,
                                                const float* __restrict__ g_t,
                                                const float* __restrict__ b2s,
                                                const float* __restrict__ b2t,
                                                float* __restrict__ z_s,
                                                float* __restrict__ z_t) {
  __shared__ u32 srcs[CAP];
  __shared__ int cnt[BNODES], excl[BNODES], st[BNODES], cur[BNODES];
  int nbkS = (NS + BNODES - 1) >> BSHIFT;
  int b = blockIdx.x;
  const u32 *hf8, *bkt;
  const float *g, *bias;
  float* z;
  int N, ec;
  if (b < nbkS) {
    hf8 = ht_f8; bkt = bktS + (size_t)b * CAP; ec = gcur[b];
    g = g_s; bias = b2s; z = z_s; N = NS;
  } else {
    b -= nbkS;
    hf8 = hs_f8; bkt = bktT + (size_t)b * CAP; ec = gcur[NBKT + b];
    g = g_t; bias = b2t; z = z_t; N = NT;
  }
  int node0 = b << BSHIFT;
  int t = threadIdx.x;
  if (t < BNODES) cnt[t] = 0;
  __syncthreads();
  for (int i = t; i < ec; i += 256) atomicAdd(&cnt[bkt[i] & (BNODES - 1)], 1);
  __syncthreads();
  if (t < BNODES) excl[t] = cnt[t];
  __syncthreads();
  for (int off = 1; off < BNODES; off <<= 1) {
    int x = 0;
    if (t < BNODES && t >= off) x = excl[t - off];
    __syncthreads();
    if (t < BNODES && t >= off) excl[t] += x;
    __syncthreads();
  }
  if (t < BNODES) {
    int s0 = excl[t] - cnt[t];
    st[t] = s0;
    cur[t] = s0;
  }
  __syncthreads();
  for (int i = t; i < ec; i += 256) {
    u32 p = bkt[i];
    int ps = atomicAdd(&cur[p & (BNODES - 1)], 1);
    srcs[ps] = p >> BSHIFT;
  }
  __syncthreads();

  int gid = t >> 4, fl = t & 15;
  for (int n = gid; n < BNODES; n += 16) {
    int node = node0 + n;
    int s = st[n], deg = cnt[n], e = s + deg;
    f32x2 a0 = {0.f, 0.f}, a1 = {0.f, 0.f};
    int i = s;
    for (; i + 4 <= e; i += 4) {
      int c0 = srcs[i], c1 = srcs[i + 1], c2 = srcs[i + 2], c3 = srcs[i + 3];
      u32 v0 = hf8[(size_t)c0 * 16 + fl];
      u32 v1 = hf8[(size_t)c1 * 16 + fl];
      u32 v2 = hf8[(size_t)c2 * 16 + fl];
      u32 v3 = hf8[(size_t)c3 * 16 + fl];
      a0 += __builtin_amdgcn_cvt_pk_f32_fp8(v0, false);
      a1 += __builtin_amdgcn_cvt_pk_f32_fp8(v0, true);
      a0 += __builtin_amdgcn_cvt_pk_f32_fp8(v1, false);
      a1 += __builtin_amdgcn_cvt_pk_f32_fp8(v1, true);
      a0 += __builtin_amdgcn_cvt_pk_f32_fp8(v2, false);
      a1 += __builtin_amdgcn_cvt_pk_f32_fp8(v2, true);
      a0 += __builtin_amdgcn_cvt_pk_f32_fp8(v3, false);
      a1 += __builtin_amdgcn_cvt_pk_f32_fp8(v3, true);
    }
    for (; i < e; ++i) {
      u32 v0 = hf8[(size_t)srcs[i] * 16 + fl];
      a0 += __builtin_amdgcn_cvt_pk_f32_fp8(v0, false);
      a1 += __builtin_amdgcn_cvt_pk_f32_fp8(v0, true);
    }
    if (node < N) {
      float inv = deg > 0 ? 1.f / (float)deg : 0.f;
      float4 gv = *reinterpret_cast<const float4*>(g + (size_t)node * 64 + fl * 4);
      float4 bv = *reinterpret_cast<const float4*>(bias + fl * 4);
      float4 r;
      r.x = a0.x * inv + gv.x + bv.x;
      r.y = a0.y * inv + gv.y + bv.y;
      r.z = a1.x * inv + gv.z + bv.z;
      r.w = a1.y * inv + gv.w + bv.w;
      *reinterpret_cast<float4*>(z + (size_t)node * 64 + fl * 4) = r;
    }
  }
}

// ---------------- layer-1 MFMA GEMM (dirs fused): xnew_bf16 = [mean|x]@[W0;W1]+bias ----------------
// mean: bf16 [M][128]; x: ORIGINAL fp32 [M][128] (packed to bf16 inline).

__global__ __launch_bounds__(256) void gemm1_dual_k(
    const u16* __restrict__ mean_s, const float* __restrict__ xs,
    const u16* __restrict__ mean_t, const float* __restrict__ xt,
    const u16* __restrict__ Wt_s0, const u16* __restrict__ Wt_s1,
    const u16* __restrict__ Wt_t0, const u16* __restrict__ Wt_t1,
    const float* __restrict__ b1s, const float* __restrict__ b1t,
    u16* __restrict__ xnew_s, u16* __restrict__ xnew_t, int NS, int NT) {
  int nb1 = (NS + 127) >> 7;
  int b = blockIdx.x;
  const u16 *A0, *Wt0, *Wt1;
  const float *X1, *bias;
  u16* out;
  int M, rowBase;
  if (b < nb1) {
    A0 = mean_s; X1 = xs; Wt0 = Wt_s0; Wt1 = Wt_s1; bias = b1s; out = xnew_s;
    M = NS; rowBase = b * 128;
  } else {
    A0 = mean_t; X1 = xt; Wt0 = Wt_t0; Wt1 = Wt_t1; bias = b1t; out = xnew_t;
    M = NT; rowBase = (b - nb1) * 128;
  }
  const int lane = threadIdx.x & 63;
  const int wid = threadIdx.x >> 6;
  const int r16 = lane & 15;
  const int kg = lane >> 4;
  rowBase += wid * 32;

  f32x4 acc[2][8];
#pragma unroll
  for (int i = 0; i < 2; ++i)
#pragma unroll
    for (int j = 0; j < 8; ++j) acc[i][j] = (f32x4){0.f, 0.f, 0.f, 0.f};

  const int r0 = min(rowBase + r16, M - 1);
  const int r1 = min(rowBase + 16 + r16, M - 1);

#pragma unroll
  for (int ch = 0; ch < 8; ++ch) {
    const int koff = (ch & 3) * 32 + kg * 8;
    bf16x8 x0, x1;
    if (ch < 4) {
      x0 = *reinterpret_cast<const bf16x8*>(A0 + (size_t)r0 * 128 + koff);
      x1 = *reinterpret_cast<const bf16x8*>(A0 + (size_t)r1 * 128 + koff);
    } else {
      float4 fa = *reinterpret_cast<const float4*>(X1 + (size_t)r0 * 128 + koff);
      float4 fb = *reinterpret_cast<const float4*>(X1 + (size_t)r0 * 128 + koff + 4);
      uint4 u0;
      u0.x = pk_bf16(fa.x, fa.y); u0.y = pk_bf16(fa.z, fa.w);
      u0.z = pk_bf16(fb.x, fb.y); u0.w = pk_bf16(fb.z, fb.w);
      x0 = __builtin_bit_cast(bf16x8, u0);
      float4 fc = *reinterpret_cast<const float4*>(X1 + (size_t)r1 * 128 + koff);
      float4 fd = *reinterpret_cast<const float4*>(X1 + (size_t)r1 * 128 + koff + 4);
      uint4 u1;
      u1.x = pk_bf16(fc.x, fc.y); u1.y = pk_bf16(fc.z, fc.w);
      u1.z = pk_bf16(fd.x, fd.y); u1.w = pk_bf16(fd.z, fd.w);
      x1 = __builtin_bit_cast(bf16x8, u1);
    }
    const u16* Wt = (ch < 4) ? Wt0 : Wt1;
#pragma unroll
    for (int cb = 0; cb < 8; ++cb) {
      bf16x8 w = *reinterpret_cast<const bf16x8*>(Wt + (size_t)(cb * 16 + r16) * 128 + koff);
      acc[0][cb] = __builtin_amdgcn_mfma_f32_16x16x32_bf16(w, x0, acc[0][cb], 0, 0, 0);
      acc[1][cb] = __builtin_amdgcn_mfma_f32_16x16x32_bf16(w, x1, acc[1][cb], 0, 0, 0);
    }
  }

#pragma unroll
  for (int cb = 0; cb < 8; ++cb) {
    float4 bv = *reinterpret_cast<const float4*>(bias + cb * 16 + kg * 4);
#pragma unroll
    for (int rb = 0; rb < 2; ++rb) {
      int row = rowBase + rb * 16 + r16;
      if (row < M) {
        f32x4 a = acc[rb][cb];
        uint2 p;
        p.x = pk_bf16(a[0] + bv.x, a[1] + bv.y);
        p.y = pk_bf16(a[2] + bv.z, a[3] + bv.w);
        *reinterpret_cast<uint2*>(out + (size_t)row * 128 + cb * 16 + kg * 4) = p;
      }
    }
  }
}

// ---------------- layer-2 MFMA GEMM (dirs fused): h_fp8 = X@Wa, g_f32 = X@Wb ----------------

__global__ __launch_bounds__(256) void gemm2_dual_k(
    const u16* __restrict__ xnew_s, const u16* __restrict__ xnew_t,
    const u16* __restrict__ WtA_s, const u16* __restrict__ WtB_s,
    const u16* __restrict__ WtA_t, const u16* __restrict__ WtB_t,
    u32* __restrict__ hs_f8, u32* __restrict__ ht_f8,
    float* __restrict__ g_s, float* __restrict__ g_t, int NS, int NT) {
  int nb1 = (NS + 127) >> 7;
  int b = blockIdx.x;
  const u16 *X, *WtA, *WtB;
  u32* h;
  float* g;
  int M, rowBase;
  if (b < nb1) {
    X = xnew_s; WtA = WtA_s; WtB = WtB_s; h = hs_f8; g = g_s; M = NS; rowBase = b * 128;
  } else {
    X = xnew_t; WtA = WtA_t; WtB = WtB_t; h = ht_f8; g = g_t; M = NT;
    rowBase = (b - nb1) * 128;
  }
  const int lane = threadIdx.x & 63;
  const int wid = threadIdx.x >> 6;
  const int r16 = lane & 15;
  const int kg = lane >> 4;
  rowBase += wid * 32;

  f32x4 acc[2][8];
#pragma unroll
  for (int i = 0; i < 2; ++i)
#pragma unroll
    for (int j = 0; j < 8; ++j) acc[i][j] = (f32x4){0.f, 0.f, 0.f, 0.f};

  const int r0 = min(rowBase + r16, M - 1);
  const int r1 = min(rowBase + 16 + r16, M - 1);

#pragma unroll
  for (int ch = 0; ch < 4; ++ch) {
    const int koff = ch * 32 + kg * 8;
    bf16x8 x0 = *reinterpret_cast<const bf16x8*>(X + (size_t)r0 * 128 + koff);
    bf16x8 x1 = *reinterpret_cast<const bf16x8*>(X + (size_t)r1 * 128 + koff);
#pragma unroll
    for (int cb = 0; cb < 8; ++cb) {
      const u16* Wt = (cb < 4) ? WtA : WtB;
      bf16x8 w = *reinterpret_cast<const bf16x8*>(Wt + (size_t)((cb & 3) * 16 + r16) * 128 + koff);
      acc[0][cb] = __builtin_amdgcn_mfma_f32_16x16x32_bf16(w, x0, acc[0][cb], 0, 0, 0);
      acc[1][cb] = __builtin_amdgcn_mfma_f32_16x16x32_bf16(w, x1, acc[1][cb], 0, 0, 0);
    }
  }

#pragma unroll
  for (int cb = 0; cb < 8; ++cb) {
#pragma unroll
    for (int rb = 0; rb < 2; ++rb) {
      int row = rowBase + rb * 16 + r16;
      if (row < M) {
        f32x4 a = acc[rb][cb];
        if (cb < 4) {
          u32 p = 0;
          p = __builtin_amdgcn_cvt_pk_fp8_f32(a[0], a[1], p, false);
          p = __builtin_amdgcn_cvt_pk_fp8_f32(a[2], a[3], p, true);
          h[(size_t)row * 16 + cb * 4 + kg] = p;
        } else {
          *reinterpret_cast<f32x4*>(g + (size_t)row * 64 + (cb - 4) * 16 + kg * 4) = a;
        }
      }
    }
  }
}

// ---------------- launch ----------------

extern "C" void kernel_launch(void* const* d_in, const int* in_sizes, int n_in,
                              void* d_out, int out_size, void* d_ws, size_t ws_size,
                              hipStream_t stream) {
  const float* x_s = (const float*)d_in[0];
  const float* x_t = (const float*)d_in[1];
  const int* s2t = (const int*)d_in[2];
  const int* t2s = (const int*)d_in[3];
  const float* W1s_l = (const float*)d_in[4];
  const float* W1s_r = (const float*)d_in[5];
  const float* b1s = (const float*)d_in[6];
  const float* W1t_l = (const float*)d_in[7];
  const float* W1t_r = (const float*)d_in[8];
  const float* b1t = (const float*)d_in[9];
  const float* W2s_l = (const float*)d_in[10];
  const float* W2s_r = (const float*)d_in[11];
  const float* b2s = (const float*)d_in[12];
  const float* W2t_l = (const float*)d_in[13];
  const float* W2t_r = (const float*)d_in[14];
  const float* b2t = (const float*)d_in[15];

  const int NS = in_sizes[0] / 128;
  const int NT = in_sizes[1] / 128;
  const int E = in_sizes[2] / 2;

  char* ws = (char*)d_ws;
  size_t off = 0;
  auto alloc = [&](size_t bytes) -> void* {
    void* p = ws + off;
    off = (off + bytes + 255) & ~(size_t)255;
    return p;
  };

  const int nbkS = cdiv(NS, BNODES);
  const int nbkT = cdiv(NT, BNODES);
  const int nblk = cdiv(E, EPB);

  int* gcur = (int*)alloc(2 * NBKT * 4);
  u16* Wt = (u16*)alloc(98304 * 2);
  u32* bktS = (u32*)alloc((size_t)nbkS * CAP * 4);
  u32* bktT = (u32*)alloc((size_t)nbkT * CAP * 4);

  // R2 ((NS+NT)*512 B): head [0,384B/node) = mean_bf -> h_f8/g; tail [384,512) = fp8 x
  char* R2 = (char*)alloc((size_t)(NS + NT) * 512);
  u16* xnew_s = (u16*)alloc((size_t)(NS + NT) * 256);  // bf16 [*][128]
  u16* xnew_t = xnew_s + (size_t)NS * 128;

  u16* mean_s = (u16*)R2;  // [NS][128] bf16
  u16* mean_t = mean_s + (size_t)NS * 128;
  u32* hs_f8 = (u32*)R2;   // [NS][16] u32 (64 fp8)
  u32* ht_f8 = hs_f8 + (size_t)NS * 16;
  float* g_s = (float*)(ht_f8 + (size_t)NT * 16);
  float* g_t = g_s + (size_t)NS * 64;

  u32* xs_f8 = (u32*)(R2 + (size_t)(NS + NT) * 384);  // [NS][32] u32
  u32* xt_f8 = xs_f8 + (size_t)NS * 32;

  u16* Wt1s_l = Wt;
  u16* Wt1s_r = Wt + 16384;
  u16* Wt1t_l = Wt + 32768;
  u16* Wt1t_r = Wt + 49152;
  u16* Wt2A_s = Wt + 65536;  // W2t_l^T (h_s)
  u16* Wt2B_s = Wt + 73728;  // W2s_r^T (g_s)
  u16* Wt2A_t = Wt + 81920;  // W2s_l^T (h_t)
  u16* Wt2B_t = Wt + 90112;  // W2t_r^T (g_t)

  float* z_s = (float*)d_out;
  float* z_t = (float*)d_out + (size_t)NS * 64;

  // conversions + bucket-cursor reset
  cvt_f8_k<<<cdiv(NS * 32 + NT * 32, 256), 256, 0, stream>>>(
      x_s, x_t, NS * 32, NT * 32, xs_f8, xt_f8);
  cvtW_k<<<48, 256, 0, stream>>>(W1s_l, W1s_r, W1t_l, W1t_r,
                                 W2t_l, W2s_r, W2s_l, W2t_r, Wt);
  hipMemsetAsync(gcur, 0, 2 * NBKT * 4, stream);

  // bucket scatter, both directions (S-dst edges from t2s; T-dst edges from s2t)
  scatfuse_k<<<2 * nblk, 256, 0, stream>>>(t2s, t2s + E, s2t, s2t + E, E, nblk,
                                           gcur, bktS, bktT);

  // ----- layer 1 -----
  agg128B_k<<<nbkS + nbkT, 256, 0, stream>>>(xs_f8, xt_f8, bktS, bktT, gcur,
                                             NS, NT, (u32*)mean_s, (u32*)mean_t);
  gemm1_dual_k<<<cdiv(NS, 128) + cdiv(NT, 128), 256, 0, stream>>>(
      mean_s, x_s, mean_t, x_t, Wt1s_l, Wt1s_r, Wt1t_l, Wt1t_r,
      b1s, b1t, xnew_s, xnew_t, NS, NT);

  // ----- layer 2 (transform-first) -----
  gemm2_dual_k<<<cdiv(NS, 128) + cdiv(NT, 128), 256, 0, stream>>>(
      xnew_s, xnew_t, Wt2A_s, Wt2B_s, Wt2A_t, Wt2B_t, hs_f8, ht_f8, g_s, g_t, NS, NT);
  agg64B_k<<<nbkS + nbkT, 256, 0, stream>>>(hs_f8, ht_f8, bktS, bktT, gcur,
                                            NS, NT, g_s, g_t, b2s, b2t, z_s, z_t);
}